// Round 12
// baseline (594.363 us; speedup 1.0000x reference)
//
#include <hip/hip_runtime.h>

#define T_STEPS 48
#define BATCH   48
#define DG      256
#define DH      512
#define S_INNER 3
#define HDSTRIDE 260   // histd row stride in u32: +4-bank skew per row, 16B-aligned

typedef _Float16 hf2 __attribute__((ext_vector_type(2)));

__device__ __forceinline__ hf2 bch(unsigned u) { return __builtin_bit_cast(hf2, u); }
__device__ __forceinline__ unsigned pkh(_Float16 a, _Float16 b) {
  hf2 v{a, b}; return __builtin_bit_cast(unsigned, v);
}
__device__ __forceinline__ float fdot2u(unsigned a, unsigned b, float c) {
#if __has_builtin(__builtin_amdgcn_fdot2)
  return __builtin_amdgcn_fdot2(bch(a), bch(b), c, false);
#else
  hf2 x = bch(a), y = bch(b);
  return fmaf((float)x.x, (float)y.x, fmaf((float)x.y, (float)y.y, c));
#endif
}
template <int CTRL>
__device__ __forceinline__ float dpp_add(float v) {
  int t = __builtin_amdgcn_update_dpp(0, __float_as_int(v), CTRL, 0xf, 0xf, true);
  return v + __int_as_float(t);
}
template <int CTRL>
__device__ __forceinline__ float dpp_mov(float v) {
  return __int_as_float(
      __builtin_amdgcn_update_dpp(0, __float_as_int(v), CTRL, 0xf, 0xf, true));
}
// 64-lane sum, result valid in lane 63; zero LDS traffic
__device__ __forceinline__ float wave64_sum63(float v) {
  v = dpp_add<0xB1>(v);    // xor1 (quad_perm)
  v = dpp_add<0x4E>(v);    // xor2 (quad_perm)
  v = dpp_add<0x141>(v);   // row_half_mirror
  v = dpp_add<0x140>(v);   // row_mirror
  v = dpp_add<0x142>(v);   // row_bcast15
  v = dpp_add<0x143>(v);   // row_bcast31 -> total in lane 63
  return v;
}
// sum over each 16-lane row, result in all 16 lanes of the row
__device__ __forceinline__ float row16_sum(float v) {
  v = dpp_add<0xB1>(v);
  v = dpp_add<0x4E>(v);
  v = dpp_add<0x141>(v);
  v = dpp_add<0x140>(v);
  return v;
}

// ---------- weight packing: Whq[j*128 + q] = 4 dims {4q..4q+3} of column j, fp16
__global__ __launch_bounds__(256)
void pack_whq(const float* __restrict__ W, uint2* __restrict__ Wq) {
  int idx = blockIdx.x * 256 + threadIdx.x;   // 65536
  int j = idx & (DH - 1), q = idx >> 9;
  float w0 = W[(size_t)(4 * q + 0) * DH + j];
  float w1 = W[(size_t)(4 * q + 1) * DH + j];
  float w2 = W[(size_t)(4 * q + 2) * DH + j];
  float w3 = W[(size_t)(4 * q + 3) * DH + j];
  uint2 o;
  o.x = pkh((_Float16)w0, (_Float16)w1);
  o.y = pkh((_Float16)w2, (_Float16)w3);
  Wq[(size_t)j * 128 + q] = o;
}

__global__ __launch_bounds__(256)
void transpose_k(const float* __restrict__ in, float* __restrict__ out, int R, int C) {
  __shared__ float tile[32][33];
  int c0 = blockIdx.x * 32, r0 = blockIdx.y * 32;
  int tx = threadIdx.x & 31, ty = threadIdx.x >> 5;
  #pragma unroll
  for (int k = 0; k < 32; k += 8)
    tile[ty + k][tx] = in[(size_t)(r0 + ty + k) * C + (c0 + tx)];
  __syncthreads();
  #pragma unroll
  for (int k = 0; k < 32; k += 8)
    out[(size_t)(c0 + ty + k) * R + (r0 + tx)] = tile[tx][ty + k];
}

__global__ __launch_bounds__(DH, 2)
void zg_kernel(const float* __restrict__ z, const float* __restrict__ WgT,
               float* __restrict__ ZG) {
  const int row0 = blockIdx.x * 8;
  const int tid = threadIdx.x;
  __shared__ __align__(16) float zl[8][DG];
  for (int i = tid; i < 8 * (DG / 4); i += DH) {
    int r = i >> 6, c = i & 63;
    ((float4*)zl[r])[c] = ((const float4*)(z + (size_t)(row0 + r) * DG))[c];
  }
  __syncthreads();
  float acc[8] = {0.f, 0.f, 0.f, 0.f, 0.f, 0.f, 0.f, 0.f};
  for (int j = 0; j < DG; j += 4) {
    float w0 = WgT[(size_t)(j + 0) * DH + tid];
    float w1 = WgT[(size_t)(j + 1) * DH + tid];
    float w2 = WgT[(size_t)(j + 2) * DH + tid];
    float w3 = WgT[(size_t)(j + 3) * DH + tid];
    #pragma unroll
    for (int r = 0; r < 8; ++r) {
      float4 zz = ((const float4*)zl[r])[j >> 2];
      acc[r] = fmaf(w0, zz.x, acc[r]);
      acc[r] = fmaf(w1, zz.y, acc[r]);
      acc[r] = fmaf(w2, zz.z, acc[r]);
      acc[r] = fmaf(w3, zz.w, acc[r]);
    }
  }
  #pragma unroll
  for (int r = 0; r < 8; ++r)
    ZG[(size_t)(row0 + r) * DH + tid] = acc[r];
}

#define HCASE2(s) \
  case (2*(s)):   hreg0[(s)] = hb0;          hreg1[(s)] = hb1;          break; \
  case (2*(s)+1): hreg0[(s)] |= (hb0 << 16); hreg1[(s)] |= (hb1 << 16); break;

#define MVACC(E, wA, wB) do {                                        \
    hf2 h0 = bch((E).y), h1 = bch((E).w);                            \
    a0 += bch((wA).x) * h0; a1 += bch((wA).y) * h0;                  \
    a2 += bch((wA).z) * h0; a3 += bch((wA).w) * h0;                  \
    b0 += bch((wB).x) * h1; b1 += bch((wB).y) * h1;                  \
    b2 += bch((wB).z) * h1; b3 += bch((wB).w) * h1;                  \
  } while (0)

#define LDW(off) (*(const uint4*)(Wb + ((off) + l16)))

// Ah for one batch: hreg . cbuf, gated by t
__device__ __forceinline__ float compute_ah(const unsigned (&hreg)[24],
                                            const unsigned* cbuf, int t) {
  const uint4* cbp = (const uint4*)cbuf;
  float A0 = 0.f, A1 = 0.f, A2 = 0.f, A3 = 0.f;
  {
    uint4 c = cbp[0];
    A0 = fdot2u(hreg[0], c.x, A0); A1 = fdot2u(hreg[1], c.y, A1);
    A2 = fdot2u(hreg[2], c.z, A2); A3 = fdot2u(hreg[3], c.w, A3);
  }
  if (t > 8) {
    uint4 c = cbp[1];
    A0 = fdot2u(hreg[4], c.x, A0); A1 = fdot2u(hreg[5], c.y, A1);
    A2 = fdot2u(hreg[6], c.z, A2); A3 = fdot2u(hreg[7], c.w, A3);
  }
  if (t > 16) {
    uint4 c = cbp[2];
    A0 = fdot2u(hreg[8], c.x, A0);  A1 = fdot2u(hreg[9], c.y, A1);
    A2 = fdot2u(hreg[10], c.z, A2); A3 = fdot2u(hreg[11], c.w, A3);
  }
  if (t > 24) {
    uint4 c = cbp[3];
    A0 = fdot2u(hreg[12], c.x, A0); A1 = fdot2u(hreg[13], c.y, A1);
    A2 = fdot2u(hreg[14], c.z, A2); A3 = fdot2u(hreg[15], c.w, A3);
  }
  if (t > 32) {
    uint4 c = cbp[4];
    A0 = fdot2u(hreg[16], c.x, A0); A1 = fdot2u(hreg[17], c.y, A1);
    A2 = fdot2u(hreg[18], c.z, A2); A3 = fdot2u(hreg[19], c.w, A3);
  }
  if (t > 40) {
    uint4 c = cbp[5];
    A0 = fdot2u(hreg[20], c.x, A0); A1 = fdot2u(hreg[21], c.y, A1);
    A2 = fdot2u(hreg[22], c.z, A2); A3 = fdot2u(hreg[23], c.w, A3);
  }
  return (A0 + A1) + (A2 + A3);
}

__device__ __forceinline__ void prefetch_rows(const unsigned* hist, int g, bool g16,
                                              int t, int dj,
                                              uint4 (&hA)[4], uint4 (&hB)[4]) {
  #pragma unroll
  for (int k = 0; k < 4; ++k) {
    hA[k] = make_uint4(0u, 0u, 0u, 0u);
    hB[k] = make_uint4(0u, 0u, 0u, 0u);
  }
  if (g < t) {
    const unsigned* rp = hist + g * HDSTRIDE + 4 * dj;
    hA[0] = *(const uint4*)(rp + 0);
    hA[1] = *(const uint4*)(rp + 64);
    hA[2] = *(const uint4*)(rp + 128);
    hA[3] = *(const uint4*)(rp + 192);
  }
  if (g16 && 32 + g < t) {
    const unsigned* rp = hist + (32 + g) * HDSTRIDE + 4 * dj;
    hB[0] = *(const uint4*)(rp + 0);
    hB[1] = *(const uint4*)(rp + 64);
    hB[2] = *(const uint4*)(rp + 128);
    hB[3] = *(const uint4*)(rp + 192);
  }
}

// dot phase for one batch: rows g (and 32+g), write c coeffs
__device__ __forceinline__ void dot_phase(const unsigned* h2c,
                                          const uint4 (&hA)[4], const uint4 (&hB)[4],
                                          bool g16, int g, int t, int dj,
                                          const float* lampow, unsigned* cbuf) {
  float pA = 0.f, pB = 0.f;
  if (g < t) {
    const unsigned* hp = h2c + 4 * dj;
    uint4 v0 = *(const uint4*)(hp + 0);
    uint4 v1 = *(const uint4*)(hp + 64);
    uint4 v2 = *(const uint4*)(hp + 128);
    uint4 v3 = *(const uint4*)(hp + 192);
    float a0 = 0.f, a1 = 0.f, a2 = 0.f, a3 = 0.f;
    a0 = fdot2u(hA[0].x, v0.x, a0); a1 = fdot2u(hA[0].y, v0.y, a1);
    a2 = fdot2u(hA[0].z, v0.z, a2); a3 = fdot2u(hA[0].w, v0.w, a3);
    a0 = fdot2u(hA[1].x, v1.x, a0); a1 = fdot2u(hA[1].y, v1.y, a1);
    a2 = fdot2u(hA[1].z, v1.z, a2); a3 = fdot2u(hA[1].w, v1.w, a3);
    a0 = fdot2u(hA[2].x, v2.x, a0); a1 = fdot2u(hA[2].y, v2.y, a1);
    a2 = fdot2u(hA[2].z, v2.z, a2); a3 = fdot2u(hA[2].w, v2.w, a3);
    a0 = fdot2u(hA[3].x, v3.x, a0); a1 = fdot2u(hA[3].y, v3.y, a1);
    a2 = fdot2u(hA[3].z, v3.z, a2); a3 = fdot2u(hA[3].w, v3.w, a3);
    pA = row16_sum((a0 + a1) + (a2 + a3));
    if (g16 && 32 + g < t) {
      float e0 = 0.f, e1 = 0.f, e2 = 0.f, e3 = 0.f;
      e0 = fdot2u(hB[0].x, v0.x, e0); e1 = fdot2u(hB[0].y, v0.y, e1);
      e2 = fdot2u(hB[0].z, v0.z, e2); e3 = fdot2u(hB[0].w, v0.w, e3);
      e0 = fdot2u(hB[1].x, v1.x, e0); e1 = fdot2u(hB[1].y, v1.y, e1);
      e2 = fdot2u(hB[1].z, v1.z, e2); e3 = fdot2u(hB[1].w, v1.w, e3);
      e0 = fdot2u(hB[2].x, v2.x, e0); e1 = fdot2u(hB[2].y, v2.y, e1);
      e2 = fdot2u(hB[2].z, v2.z, e2); e3 = fdot2u(hB[2].w, v2.w, e3);
      e0 = fdot2u(hB[3].x, v3.x, e0); e1 = fdot2u(hB[3].y, v3.y, e1);
      e2 = fdot2u(hB[3].z, v3.z, e2); e3 = fdot2u(hB[3].w, v3.w, e3);
      pB = row16_sum((e0 + e1) + (e2 + e3));
    }
  }
  if (dj == 0) {
    float ccA = (g < t) ? pA * lampow[t - 1 - g] : 0.f;
    _Float16 chA = (_Float16)ccA;
    ((unsigned short*)cbuf)[g] = __builtin_bit_cast(unsigned short, chA);
    if (g16) {
      int rB = 32 + g;
      float ccB = (rB < t) ? pB * lampow[t - 1 - rB] : 0.f;
      _Float16 chB = (_Float16)ccB;
      ((unsigned short*)cbuf)[rB] = __builtin_bit_cast(unsigned short, chB);
    }
  }
}

__global__ __launch_bounds__(512, 2)
void rnn_main(const float* __restrict__ ZG, const uint2* __restrict__ Whq,
              const float* __restrict__ bh, const float* __restrict__ gamma,
              const float* __restrict__ beta, const float* __restrict__ W_head,
              const float* __restrict__ b_head, const float* __restrict__ clean,
              float* __restrict__ outbuf) {
  const int bat0 = blockIdx.x * 2, bat1 = bat0 + 1;
  const int tid  = threadIdx.x;         // 512 threads = 8 waves, 2 batches
  const int lane = tid & 63;
  const int wv   = tid >> 6;            // wave = matvec slice = active region
  const int dim  = tid;                 // owner dim
  const int g    = tid >> 4;            // dot group 0..31
  const int dj   = tid & 15;            // chunk id within row
  const bool g16 = tid < 256;           // groups 0..15 take rows g and 32+g

  __shared__ __align__(16) unsigned histd[2][T_STEPS * HDSTRIDE];  // ~99.8KB
  __shared__ __align__(16) float    pm[2][8 * DH];                 // 32KB
  __shared__ __align__(16) uint2    APr[2][8 * 64];                // 8KB
  __shared__ __align__(16) unsigned h2cur[2][256];                 // 2KB
  __shared__ __align__(16) unsigned cbufh2[2][32];                 // 256B
  __shared__ __align__(16) float    hcur[2][DH];                   // 4KB
  __shared__ __align__(16) float    pred[2][DG];                   // 2KB
  __shared__ __align__(16) float2   red[2][8];
  __shared__ float  red4[2][32];
  __shared__ int    wcntp[2][8];
  __shared__ float  lampow[T_STEPS];

  const float g_i  = gamma[dim];
  const float be_i = beta[dim];
  const float bh_i = bh[dim];
  if (tid == 0) {
    float pw = 0.5f;                    // eta folded in
    for (int k = 0; k < T_STEPS; ++k) { lampow[k] = pw; pw *= 0.95f; }
  }
  unsigned hreg0[24], hreg1[24];        // owner's fp16 history columns
  #pragma unroll
  for (int k = 0; k < 24; ++k) { hreg0[k] = 0u; hreg1[k] = 0u; }

  const char* Wb = (const char*)Whq;    // SGPR base for saddr-form gathers
  const unsigned l16 = (unsigned)(lane << 4);
  __syncthreads();

  for (int t = 0; t < T_STEPS; ++t) {
    float zg0 = ZG[((size_t)t * BATCH + bat0) * DH + dim];
    float zg1 = ZG[((size_t)t * BATCH + bat1) * DH + dim];

    // batch-0 dot rows before matvec (caps VGPR peak); batch-1 rows after
    uint4 hA0[4], hB0[4], hA1[4], hB1[4];
    prefetch_rows(histd[0], g, g16, t, dj, hA0, hB0);

    // ---- matvec for both batches (sequential, each 4-deep pipelined)
    #pragma unroll
    for (int bb = 0; bb < 2; ++bb) {
      hf2 a0{}, a1{}, a2{}, a3{}, b0{}, b1{}, b2{}, b3{};
      if (t > 0) {
        const int n = wcntp[bb][wv];    // multiple of 8 (or 0), uniform in wave
        if (n > 0) {
          const uint4* ap4 = (const uint4*)(APr[bb] + wv * 64);
          const int G = n >> 1;          // multiple of 4, >= 4
          uint4 E0 = ap4[0], E1 = ap4[1], E2 = ap4[2], E3 = ap4[3];
          uint4 wA0 = LDW(E0.x), wB0 = LDW(E0.z);
          uint4 wA1 = LDW(E1.x), wB1 = LDW(E1.z);
          uint4 wA2 = LDW(E2.x), wB2 = LDW(E2.z);
          uint4 wA3 = LDW(E3.x), wB3 = LDW(E3.z);
          for (int grp = 4; grp < G; grp += 4) {
            uint4 F0 = ap4[grp], F1 = ap4[grp + 1];
            uint4 F2 = ap4[grp + 2], F3 = ap4[grp + 3];
            uint4 xA0 = LDW(F0.x), xB0 = LDW(F0.z);
            uint4 xA1 = LDW(F1.x), xB1 = LDW(F1.z);
            uint4 xA2 = LDW(F2.x), xB2 = LDW(F2.z);
            uint4 xA3 = LDW(F3.x), xB3 = LDW(F3.z);
            MVACC(E0, wA0, wB0); MVACC(E1, wA1, wB1);
            MVACC(E2, wA2, wB2); MVACC(E3, wA3, wB3);
            E0 = F0; E1 = F1; E2 = F2; E3 = F3;
            wA0 = xA0; wB0 = xB0; wA1 = xA1; wB1 = xB1;
            wA2 = xA2; wB2 = xB2; wA3 = xA3; wB3 = xB3;
          }
          MVACC(E0, wA0, wB0); MVACC(E1, wA1, wB1);
          MVACC(E2, wA2, wB2); MVACC(E3, wA3, wB3);
        }
      }
      float4 s0, s1;
      s0.x = (float)a0.x + (float)b0.x; s0.y = (float)a0.y + (float)b0.y;
      s0.z = (float)a1.x + (float)b1.x; s0.w = (float)a1.y + (float)b1.y;
      s1.x = (float)a2.x + (float)b2.x; s1.y = (float)a2.y + (float)b2.y;
      s1.z = (float)a3.x + (float)b3.x; s1.w = (float)a3.y + (float)b3.y;
      float4* pmw = (float4*)(pm[bb] + wv * DH);
      pmw[2 * lane + 0] = s0;
      pmw[2 * lane + 1] = s1;
    }
    prefetch_rows(histd[1], g, g16, t, dj, hA1, hB1);
    __syncthreads();                                     // B0

    float base0 = bh_i + zg0, base1 = bh_i + zg1;
    if (t > 0) {
      float p0 = 0.f, p1 = 0.f;
      #pragma unroll
      for (int sl = 0; sl < 8; ++sl) {
        p0 += pm[0][sl * DH + dim];
        p1 += pm[1][sl * DH + dim];
      }
      base0 += p0; base1 += p1;
    }

    for (int inr = 0; inr <= S_INNER; ++inr) {
      // ---- phase A: x = base + Ah for both batches; DPP sums; lane63 publishes
      float x0, x1;
      {
        float Ah0 = 0.f, Ah1 = 0.f;
        if (inr > 0 && t > 0) {
          Ah0 = compute_ah(hreg0, cbufh2[0], t);
          Ah1 = compute_ah(hreg1, cbufh2[1], t);
        }
        x0 = base0 + Ah0;
        x1 = base1 + Ah1;
        float sa0 = wave64_sum63(x0);
        float sb0 = wave64_sum63(x0 * x0);
        float sa1 = wave64_sum63(x1);
        float sb1 = wave64_sum63(x1 * x1);
        if (lane == 63) {
          red[0][wv] = make_float2(sa0, sb0);
          red[1][wv] = make_float2(sa1, sb1);
        }
      }
      __syncthreads();                                   // B1
      float mu0, rstd0, mu1, rstd1;
      {
        const float4* rr = (const float4*)red[0];
        float4 r0 = rr[0], r1 = rr[1], r2 = rr[2], r3 = rr[3];
        float s  = ((r0.x + r1.x) + (r2.x + r3.x)) + ((r0.z + r1.z) + (r2.z + r3.z));
        float s2 = ((r0.y + r1.y) + (r2.y + r3.y)) + ((r0.w + r1.w) + (r2.w + r3.w));
        const float inv = 1.f / (float)DH;
        mu0 = s * inv;
        rstd0 = rsqrtf(s2 * inv - mu0 * mu0 + 1e-5f);
      }
      {
        const float4* rr = (const float4*)red[1];
        float4 r0 = rr[0], r1 = rr[1], r2 = rr[2], r3 = rr[3];
        float s  = ((r0.x + r1.x) + (r2.x + r3.x)) + ((r0.z + r1.z) + (r2.z + r3.z));
        float s2 = ((r0.y + r1.y) + (r2.y + r3.y)) + ((r0.w + r1.w) + (r2.w + r3.w));
        const float inv = 1.f / (float)DH;
        mu1 = s * inv;
        rstd1 = rsqrtf(s2 * inv - mu1 * mu1 + 1e-5f);
      }

      if (inr < S_INNER) {
        // ---- phase B: LN -> h, publish packed pairs (both batches)
        {
          float h0 = fmaxf(fmaf((x0 - mu0) * rstd0, g_i, be_i), 0.f);
          float h1 = fmaxf(fmaf((x1 - mu1) * rstd1, g_i, be_i), 0.f);
          float hn0 = dpp_mov<0xB1>(h0);
          float hn1 = dpp_mov<0xB1>(h1);
          if (!(dim & 1)) {
            h2cur[0][dim >> 1] = pkh((_Float16)h0, (_Float16)hn0);
            h2cur[1][dim >> 1] = pkh((_Float16)h1, (_Float16)hn1);
          }
        }
        __syncthreads();                                 // B2
        // ---- phase C: dots for both batches
        dot_phase(h2cur[0], hA0, hB0, g16, g, t, dj, lampow, cbufh2[0]);
        dot_phase(h2cur[1], hA1, hB1, g16, g, t, dj, lampow, cbufh2[1]);
        __syncthreads();                                 // B3
      } else {
        // ---- final inner: materialize h, append history, active lists
        {
          float h0 = fmaxf(fmaf((x0 - mu0) * rstd0, g_i, be_i), 0.f);
          float h1 = fmaxf(fmaf((x1 - mu1) * rstd1, g_i, be_i), 0.f);
          unsigned hb0 = (unsigned)__builtin_bit_cast(unsigned short, (_Float16)h0);
          unsigned hb1 = (unsigned)__builtin_bit_cast(unsigned short, (_Float16)h1);
          float hn0 = dpp_mov<0xB1>(h0);
          float hn1 = dpp_mov<0xB1>(h1);
          if (!(dim & 1)) {
            histd[0][t * HDSTRIDE + (dim >> 1)] = pkh((_Float16)h0, (_Float16)hn0);
            histd[1][t * HDSTRIDE + (dim >> 1)] = pkh((_Float16)h1, (_Float16)hn1);
          }
          switch (t) {
            HCASE2(0)  HCASE2(1)  HCASE2(2)  HCASE2(3)  HCASE2(4)  HCASE2(5)
            HCASE2(6)  HCASE2(7)  HCASE2(8)  HCASE2(9)  HCASE2(10) HCASE2(11)
            HCASE2(12) HCASE2(13) HCASE2(14) HCASE2(15) HCASE2(16) HCASE2(17)
            HCASE2(18) HCASE2(19) HCASE2(20) HCASE2(21) HCASE2(22) HCASE2(23)
          }
          if (t == T_STEPS - 1) { hcur[0][dim] = h0; hcur[1][dim] = h1; }
          {
            unsigned long long mb = __ballot(h0 != 0.f);
            int myoff = __popcll(mb & ((1ull << lane) - 1ull));
            int wc  = __popcll(mb);
            int wcp = (wc + 7) & ~7;
            if (h0 != 0.f) {
              _Float16 hh = (_Float16)h0;
              uint2 ent; ent.x = (unsigned)(dim << 10); ent.y = pkh(hh, hh);
              APr[0][wv * 64 + myoff] = ent;
            } else {
              int inact = lane - myoff;
              if (inact < wcp - wc) {
                uint2 zz; zz.x = 0u; zz.y = 0u;
                APr[0][wv * 64 + wc + inact] = zz;
              }
            }
            if (lane == 0) wcntp[0][wv] = wcp;
          }
          {
            unsigned long long mb = __ballot(h1 != 0.f);
            int myoff = __popcll(mb & ((1ull << lane) - 1ull));
            int wc  = __popcll(mb);
            int wcp = (wc + 7) & ~7;
            if (h1 != 0.f) {
              _Float16 hh = (_Float16)h1;
              uint2 ent; ent.x = (unsigned)(dim << 10); ent.y = pkh(hh, hh);
              APr[1][wv * 64 + myoff] = ent;
            } else {
              int inact = lane - myoff;
              if (inact < wcp - wc) {
                uint2 zz; zz.x = 0u; zz.y = 0u;
                APr[1][wv * 64 + wc + inact] = zz;
              }
            }
            if (lane == 0) wcntp[1][wv] = wcp;
          }
        }
        __syncthreads();                                 // B3f
      }
    }
  }

  // ---- epilogue: pred = h @ W_head^T + b_head, then loss/acc (both batches)
  #pragma unroll
  for (int bb = 0; bb < 2; ++bb) {
    for (int r = wv; r < DG; r += 8) {
      const float4* w4  = (const float4*)(W_head + (size_t)r * DH);
      const float4* hc4 = (const float4*)hcur[bb];
      float4 a4 = w4[lane];      float4 c4 = hc4[lane];
      float4 a5 = w4[lane + 64]; float4 c5 = hc4[lane + 64];
      float pdot = a4.x * c4.x + a4.y * c4.y + a4.z * c4.z + a4.w * c4.w
                 + a5.x * c5.x + a5.y * c5.y + a5.z * c5.z + a5.w * c5.w;
      pdot = wave64_sum63(pdot);
      if (lane == 63) pred[bb][r] = pdot + b_head[r];
    }
  }
  __syncthreads();

  #pragma unroll
  for (int bb = 0; bb < 2; ++bb) {
    const int bat = (bb == 0) ? bat0 : bat1;
    float sq = 0.f, pc = 0.f, pp = 0.f, cc = 0.f;
    if (tid < DG) {
      float pv = pred[bb][tid];
      float cv = clean[(size_t)bat * DG + tid];
      float d = pv - cv;
      sq = d * d; pc = pv * cv; pp = pv * pv; cc = cv * cv;
    }
    #pragma unroll
    for (int off = 32; off > 0; off >>= 1) {
      sq += __shfl_xor(sq, off, 64);
      pc += __shfl_xor(pc, off, 64);
      pp += __shfl_xor(pp, off, 64);
      cc += __shfl_xor(cc, off, 64);
    }
    if (lane == 0) {
      red4[bb][wv * 4 + 0] = sq; red4[bb][wv * 4 + 1] = pc;
      red4[bb][wv * 4 + 2] = pp; red4[bb][wv * 4 + 3] = cc;
    }
  }
  __syncthreads();
  if (tid < 2) {
    const int bat = (tid == 0) ? bat0 : bat1;
    float Sq = 0.f, Pc = 0.f, Pp = 0.f, Cc = 0.f;
    #pragma unroll
    for (int w = 0; w < 8; ++w) {
      Sq += red4[tid][w * 4 + 0]; Pc += red4[tid][w * 4 + 1];
      Pp += red4[tid][w * 4 + 2]; Cc += red4[tid][w * 4 + 3];
    }
    outbuf[bat]         = Sq / (Cc + 1e-6f);
    outbuf[BATCH + bat] = Pc / ((sqrtf(Pp) + 1e-6f) * (sqrtf(Cc) + 1e-6f));
  }
}

__global__ __launch_bounds__(64)
void finalize_k(const float* __restrict__ outbuf, float* __restrict__ out) {
  int tid = threadIdx.x;
  float l = (tid < BATCH) ? outbuf[tid] : 0.f;
  float a = (tid < BATCH) ? outbuf[BATCH + tid] : 0.f;
  #pragma unroll
  for (int off = 32; off > 0; off >>= 1) {
    l += __shfl_xor(l, off, 64);
    a += __shfl_xor(a, off, 64);
  }
  if (tid == 0) {
    out[0] = l * (1.f / (float)BATCH);
    out[1] = a * (1.f / (float)BATCH);
  }
}

extern "C" void kernel_launch(void* const* d_in, const int* in_sizes, int n_in,
                              void* d_out, int out_size, void* d_ws, size_t ws_size,
                              hipStream_t stream) {
  (void)in_sizes; (void)n_in; (void)out_size; (void)ws_size;
  const float* z      = (const float*)d_in[0];
  const float* clean  = (const float*)d_in[1];
  const float* W_h    = (const float*)d_in[2];
  const float* W_g    = (const float*)d_in[3];
  const float* b_h    = (const float*)d_in[4];
  const float* gamma  = (const float*)d_in[5];
  const float* beta   = (const float*)d_in[6];
  const float* W_head = (const float*)d_in[7];
  const float* b_head = (const float*)d_in[8];

  float* wsf     = (float*)d_ws;
  uint2* Whq     = (uint2*)wsf;                           // 65536 uint2
  float* WgT     = wsf + 131072;                          // 256*512
  float* ZG      = WgT + (size_t)DG * DH;                 // 2304*512
  float* outbuf  = ZG + (size_t)T_STEPS * BATCH * DH;     // 96

  hipLaunchKernelGGL(pack_whq, dim3(256), dim3(256), 0, stream, W_h, Whq);
  hipLaunchKernelGGL(transpose_k, dim3(DG / 32, DH / 32), dim3(256), 0, stream,
                     W_g, WgT, DH, DG);
  hipLaunchKernelGGL(zg_kernel, dim3((T_STEPS * BATCH) / 8), dim3(DH), 0, stream,
                     z, WgT, ZG);
  hipLaunchKernelGGL(rnn_main, dim3(BATCH / 2), dim3(512), 0, stream,
                     ZG, Whq, b_h, gamma, beta, W_head, b_head, clean, outbuf);
  hipLaunchKernelGGL(finalize_k, dim3(1), dim3(64), 0, stream,
                     outbuf, (float*)d_out);
}

// Round 13
// 594.253 us; speedup vs baseline: 1.0002x; 1.0002x over previous
//
#include <hip/hip_runtime.h>

#define T_STEPS 48
#define BATCH   48
#define DG      256
#define DH      512
#define S_INNER 3
#define HDSTRIDE 260   // histd row stride in u32: +4-bank skew per row, 16B-aligned

typedef _Float16 hf2 __attribute__((ext_vector_type(2)));

__device__ __forceinline__ hf2 bch(unsigned u) { return __builtin_bit_cast(hf2, u); }
__device__ __forceinline__ unsigned pkh(_Float16 a, _Float16 b) {
  hf2 v{a, b}; return __builtin_bit_cast(unsigned, v);
}
__device__ __forceinline__ float fdot2u(unsigned a, unsigned b, float c) {
#if __has_builtin(__builtin_amdgcn_fdot2)
  return __builtin_amdgcn_fdot2(bch(a), bch(b), c, false);
#else
  hf2 x = bch(a), y = bch(b);
  return fmaf((float)x.x, (float)y.x, fmaf((float)x.y, (float)y.y, c));
#endif
}
template <int CTRL>
__device__ __forceinline__ float dpp_add(float v) {
  int t = __builtin_amdgcn_update_dpp(0, __float_as_int(v), CTRL, 0xf, 0xf, true);
  return v + __int_as_float(t);
}
template <int CTRL>
__device__ __forceinline__ float dpp_mov(float v) {
  return __int_as_float(
      __builtin_amdgcn_update_dpp(0, __float_as_int(v), CTRL, 0xf, 0xf, true));
}
// 64-lane sum, result valid in lane 63; zero LDS traffic
__device__ __forceinline__ float wave64_sum63(float v) {
  v = dpp_add<0xB1>(v);    // xor1 (quad_perm)
  v = dpp_add<0x4E>(v);    // xor2 (quad_perm)
  v = dpp_add<0x141>(v);   // row_half_mirror
  v = dpp_add<0x140>(v);   // row_mirror
  v = dpp_add<0x142>(v);   // row_bcast15
  v = dpp_add<0x143>(v);   // row_bcast31 -> total in lane 63
  return v;
}
// sum over each 16-lane row, result in all 16 lanes of the row
__device__ __forceinline__ float row16_sum(float v) {
  v = dpp_add<0xB1>(v);
  v = dpp_add<0x4E>(v);
  v = dpp_add<0x141>(v);
  v = dpp_add<0x140>(v);
  return v;
}

// ---------- weight packing: Whq[j*128 + q] = 4 dims {4q..4q+3} of column j, fp16
__global__ __launch_bounds__(256)
void pack_whq(const float* __restrict__ W, uint2* __restrict__ Wq) {
  int idx = blockIdx.x * 256 + threadIdx.x;   // 65536
  int j = idx & (DH - 1), q = idx >> 9;
  float w0 = W[(size_t)(4 * q + 0) * DH + j];
  float w1 = W[(size_t)(4 * q + 1) * DH + j];
  float w2 = W[(size_t)(4 * q + 2) * DH + j];
  float w3 = W[(size_t)(4 * q + 3) * DH + j];
  uint2 o;
  o.x = pkh((_Float16)w0, (_Float16)w1);
  o.y = pkh((_Float16)w2, (_Float16)w3);
  Wq[(size_t)j * 128 + q] = o;
}

__global__ __launch_bounds__(256)
void transpose_k(const float* __restrict__ in, float* __restrict__ out, int R, int C) {
  __shared__ float tile[32][33];
  int c0 = blockIdx.x * 32, r0 = blockIdx.y * 32;
  int tx = threadIdx.x & 31, ty = threadIdx.x >> 5;
  #pragma unroll
  for (int k = 0; k < 32; k += 8)
    tile[ty + k][tx] = in[(size_t)(r0 + ty + k) * C + (c0 + tx)];
  __syncthreads();
  #pragma unroll
  for (int k = 0; k < 32; k += 8)
    out[(size_t)(c0 + ty + k) * R + (r0 + tx)] = tile[tx][ty + k];
}

__global__ __launch_bounds__(DH, 2)
void zg_kernel(const float* __restrict__ z, const float* __restrict__ WgT,
               float* __restrict__ ZG) {
  const int row0 = blockIdx.x * 8;
  const int tid = threadIdx.x;
  __shared__ __align__(16) float zl[8][DG];
  for (int i = tid; i < 8 * (DG / 4); i += DH) {
    int r = i >> 6, c = i & 63;
    ((float4*)zl[r])[c] = ((const float4*)(z + (size_t)(row0 + r) * DG))[c];
  }
  __syncthreads();
  float acc[8] = {0.f, 0.f, 0.f, 0.f, 0.f, 0.f, 0.f, 0.f};
  for (int j = 0; j < DG; j += 4) {
    float w0 = WgT[(size_t)(j + 0) * DH + tid];
    float w1 = WgT[(size_t)(j + 1) * DH + tid];
    float w2 = WgT[(size_t)(j + 2) * DH + tid];
    float w3 = WgT[(size_t)(j + 3) * DH + tid];
    #pragma unroll
    for (int r = 0; r < 8; ++r) {
      float4 zz = ((const float4*)zl[r])[j >> 2];
      acc[r] = fmaf(w0, zz.x, acc[r]);
      acc[r] = fmaf(w1, zz.y, acc[r]);
      acc[r] = fmaf(w2, zz.z, acc[r]);
      acc[r] = fmaf(w3, zz.w, acc[r]);
    }
  }
  #pragma unroll
  for (int r = 0; r < 8; ++r)
    ZG[(size_t)(row0 + r) * DH + tid] = acc[r];
}

#define HCASE2(s) \
  case (2*(s)):   hreg0[(s)] = hb0;          hreg1[(s)] = hb1;          break; \
  case (2*(s)+1): hreg0[(s)] |= (hb0 << 16); hreg1[(s)] |= (hb1 << 16); break;

#define MVACC(E, wA, wB) do {                                        \
    hf2 h0 = bch((E).y), h1 = bch((E).w);                            \
    a0 += bch((wA).x) * h0; a1 += bch((wA).y) * h0;                  \
    a2 += bch((wA).z) * h0; a3 += bch((wA).w) * h0;                  \
    b0 += bch((wB).x) * h1; b1 += bch((wB).y) * h1;                  \
    b2 += bch((wB).z) * h1; b3 += bch((wB).w) * h1;                  \
  } while (0)

#define LDW(off) (*(const uint4*)(Wb + ((off) + l16)))

// Ah for one batch: hreg . cbuf, gated by t
__device__ __forceinline__ float compute_ah(const unsigned (&hreg)[24],
                                            const unsigned* cbuf, int t) {
  const uint4* cbp = (const uint4*)cbuf;
  float A0 = 0.f, A1 = 0.f, A2 = 0.f, A3 = 0.f;
  {
    uint4 c = cbp[0];
    A0 = fdot2u(hreg[0], c.x, A0); A1 = fdot2u(hreg[1], c.y, A1);
    A2 = fdot2u(hreg[2], c.z, A2); A3 = fdot2u(hreg[3], c.w, A3);
  }
  if (t > 8) {
    uint4 c = cbp[1];
    A0 = fdot2u(hreg[4], c.x, A0); A1 = fdot2u(hreg[5], c.y, A1);
    A2 = fdot2u(hreg[6], c.z, A2); A3 = fdot2u(hreg[7], c.w, A3);
  }
  if (t > 16) {
    uint4 c = cbp[2];
    A0 = fdot2u(hreg[8], c.x, A0);  A1 = fdot2u(hreg[9], c.y, A1);
    A2 = fdot2u(hreg[10], c.z, A2); A3 = fdot2u(hreg[11], c.w, A3);
  }
  if (t > 24) {
    uint4 c = cbp[3];
    A0 = fdot2u(hreg[12], c.x, A0); A1 = fdot2u(hreg[13], c.y, A1);
    A2 = fdot2u(hreg[14], c.z, A2); A3 = fdot2u(hreg[15], c.w, A3);
  }
  if (t > 32) {
    uint4 c = cbp[4];
    A0 = fdot2u(hreg[16], c.x, A0); A1 = fdot2u(hreg[17], c.y, A1);
    A2 = fdot2u(hreg[18], c.z, A2); A3 = fdot2u(hreg[19], c.w, A3);
  }
  if (t > 40) {
    uint4 c = cbp[5];
    A0 = fdot2u(hreg[20], c.x, A0); A1 = fdot2u(hreg[21], c.y, A1);
    A2 = fdot2u(hreg[22], c.z, A2); A3 = fdot2u(hreg[23], c.w, A3);
  }
  return (A0 + A1) + (A2 + A3);
}

__device__ __forceinline__ void prefetch_rows(const unsigned* hist, int g, bool g16,
                                              int t, int dj,
                                              uint4 (&hA)[4], uint4 (&hB)[4]) {
  #pragma unroll
  for (int k = 0; k < 4; ++k) {
    hA[k] = make_uint4(0u, 0u, 0u, 0u);
    hB[k] = make_uint4(0u, 0u, 0u, 0u);
  }
  if (g < t) {
    const unsigned* rp = hist + g * HDSTRIDE + 4 * dj;
    hA[0] = *(const uint4*)(rp + 0);
    hA[1] = *(const uint4*)(rp + 64);
    hA[2] = *(const uint4*)(rp + 128);
    hA[3] = *(const uint4*)(rp + 192);
  }
  if (g16 && 32 + g < t) {
    const unsigned* rp = hist + (32 + g) * HDSTRIDE + 4 * dj;
    hB[0] = *(const uint4*)(rp + 0);
    hB[1] = *(const uint4*)(rp + 64);
    hB[2] = *(const uint4*)(rp + 128);
    hB[3] = *(const uint4*)(rp + 192);
  }
}

// dot phase for one batch: rows g (and 32+g), write c coeffs
__device__ __forceinline__ void dot_phase(const unsigned* h2c,
                                          const uint4 (&hA)[4], const uint4 (&hB)[4],
                                          bool g16, int g, int t, int dj,
                                          const float* lampow, unsigned* cbuf) {
  float pA = 0.f, pB = 0.f;
  if (g < t) {
    const unsigned* hp = h2c + 4 * dj;
    uint4 v0 = *(const uint4*)(hp + 0);
    uint4 v1 = *(const uint4*)(hp + 64);
    uint4 v2 = *(const uint4*)(hp + 128);
    uint4 v3 = *(const uint4*)(hp + 192);
    float a0 = 0.f, a1 = 0.f, a2 = 0.f, a3 = 0.f;
    a0 = fdot2u(hA[0].x, v0.x, a0); a1 = fdot2u(hA[0].y, v0.y, a1);
    a2 = fdot2u(hA[0].z, v0.z, a2); a3 = fdot2u(hA[0].w, v0.w, a3);
    a0 = fdot2u(hA[1].x, v1.x, a0); a1 = fdot2u(hA[1].y, v1.y, a1);
    a2 = fdot2u(hA[1].z, v1.z, a2); a3 = fdot2u(hA[1].w, v1.w, a3);
    a0 = fdot2u(hA[2].x, v2.x, a0); a1 = fdot2u(hA[2].y, v2.y, a1);
    a2 = fdot2u(hA[2].z, v2.z, a2); a3 = fdot2u(hA[2].w, v2.w, a3);
    a0 = fdot2u(hA[3].x, v3.x, a0); a1 = fdot2u(hA[3].y, v3.y, a1);
    a2 = fdot2u(hA[3].z, v3.z, a2); a3 = fdot2u(hA[3].w, v3.w, a3);
    pA = row16_sum((a0 + a1) + (a2 + a3));
    if (g16 && 32 + g < t) {
      float e0 = 0.f, e1 = 0.f, e2 = 0.f, e3 = 0.f;
      e0 = fdot2u(hB[0].x, v0.x, e0); e1 = fdot2u(hB[0].y, v0.y, e1);
      e2 = fdot2u(hB[0].z, v0.z, e2); e3 = fdot2u(hB[0].w, v0.w, e3);
      e0 = fdot2u(hB[1].x, v1.x, e0); e1 = fdot2u(hB[1].y, v1.y, e1);
      e2 = fdot2u(hB[1].z, v1.z, e2); e3 = fdot2u(hB[1].w, v1.w, e3);
      e0 = fdot2u(hB[2].x, v2.x, e0); e1 = fdot2u(hB[2].y, v2.y, e1);
      e2 = fdot2u(hB[2].z, v2.z, e2); e3 = fdot2u(hB[2].w, v2.w, e3);
      e0 = fdot2u(hB[3].x, v3.x, e0); e1 = fdot2u(hB[3].y, v3.y, e1);
      e2 = fdot2u(hB[3].z, v3.z, e2); e3 = fdot2u(hB[3].w, v3.w, e3);
      pB = row16_sum((e0 + e1) + (e2 + e3));
    }
  }
  if (dj == 0) {
    float ccA = (g < t) ? pA * lampow[t - 1 - g] : 0.f;
    _Float16 chA = (_Float16)ccA;
    ((unsigned short*)cbuf)[g] = __builtin_bit_cast(unsigned short, chA);
    if (g16) {
      int rB = 32 + g;
      float ccB = (rB < t) ? pB * lampow[t - 1 - rB] : 0.f;
      _Float16 chB = (_Float16)ccB;
      ((unsigned short*)cbuf)[rB] = __builtin_bit_cast(unsigned short, chB);
    }
  }
}

__global__ __launch_bounds__(512, 1)
void rnn_main(const float* __restrict__ ZG, const uint2* __restrict__ Whq,
              const float* __restrict__ bh, const float* __restrict__ gamma,
              const float* __restrict__ beta, const float* __restrict__ W_head,
              const float* __restrict__ b_head, const float* __restrict__ clean,
              float* __restrict__ outbuf) {
  const int bat0 = blockIdx.x * 2, bat1 = bat0 + 1;
  const int tid  = threadIdx.x;         // 512 threads = 8 waves, 2 batches
  const int lane = tid & 63;
  const int wv   = tid >> 6;            // wave = matvec slice = active region
  const int dim  = tid;                 // owner dim
  const int g    = tid >> 4;            // dot group 0..31
  const int dj   = tid & 15;            // chunk id within row
  const bool g16 = tid < 256;           // groups 0..15 take rows g and 32+g

  __shared__ __align__(16) unsigned histd[2][T_STEPS * HDSTRIDE];  // ~99.8KB
  __shared__ __align__(16) float    pm[2][8 * DH];                 // 32KB
  __shared__ __align__(16) uint2    APr[2][8 * 64];                // 8KB
  __shared__ __align__(16) unsigned h2cur[2][256];                 // 2KB
  __shared__ __align__(16) unsigned cbufh2[2][32];                 // 256B
  __shared__ __align__(16) float    hcur[2][DH];                   // 4KB
  __shared__ __align__(16) float    pred[2][DG];                   // 2KB
  __shared__ __align__(16) float2   red[2][8];
  __shared__ float  red4[2][32];
  __shared__ int    wcntp[2][8];
  __shared__ float  lampow[T_STEPS];

  const float g_i  = gamma[dim];
  const float be_i = beta[dim];
  const float bh_i = bh[dim];
  if (tid == 0) {
    float pw = 0.5f;                    // eta folded in
    for (int k = 0; k < T_STEPS; ++k) { lampow[k] = pw; pw *= 0.95f; }
  }
  unsigned hreg0[24], hreg1[24];        // owner's fp16 history columns
  #pragma unroll
  for (int k = 0; k < 24; ++k) { hreg0[k] = 0u; hreg1[k] = 0u; }

  const char* Wb = (const char*)Whq;    // SGPR base for saddr-form gathers
  const unsigned l16 = (unsigned)(lane << 4);
  __syncthreads();

  for (int t = 0; t < T_STEPS; ++t) {
    float zg0 = ZG[((size_t)t * BATCH + bat0) * DH + dim];
    float zg1 = ZG[((size_t)t * BATCH + bat1) * DH + dim];

    // batch-0 dot rows before matvec (caps VGPR peak); batch-1 rows after
    uint4 hA0[4], hB0[4], hA1[4], hB1[4];
    prefetch_rows(histd[0], g, g16, t, dj, hA0, hB0);

    // ---- matvec for both batches (sequential, each 4-deep pipelined)
    #pragma unroll
    for (int bb = 0; bb < 2; ++bb) {
      hf2 a0{}, a1{}, a2{}, a3{}, b0{}, b1{}, b2{}, b3{};
      if (t > 0) {
        const int n = wcntp[bb][wv];    // multiple of 8 (or 0), uniform in wave
        if (n > 0) {
          const uint4* ap4 = (const uint4*)(APr[bb] + wv * 64);
          const int G = n >> 1;          // multiple of 4, >= 4
          uint4 E0 = ap4[0], E1 = ap4[1], E2 = ap4[2], E3 = ap4[3];
          uint4 wA0 = LDW(E0.x), wB0 = LDW(E0.z);
          uint4 wA1 = LDW(E1.x), wB1 = LDW(E1.z);
          uint4 wA2 = LDW(E2.x), wB2 = LDW(E2.z);
          uint4 wA3 = LDW(E3.x), wB3 = LDW(E3.z);
          for (int grp = 4; grp < G; grp += 4) {
            uint4 F0 = ap4[grp], F1 = ap4[grp + 1];
            uint4 F2 = ap4[grp + 2], F3 = ap4[grp + 3];
            uint4 xA0 = LDW(F0.x), xB0 = LDW(F0.z);
            uint4 xA1 = LDW(F1.x), xB1 = LDW(F1.z);
            uint4 xA2 = LDW(F2.x), xB2 = LDW(F2.z);
            uint4 xA3 = LDW(F3.x), xB3 = LDW(F3.z);
            MVACC(E0, wA0, wB0); MVACC(E1, wA1, wB1);
            MVACC(E2, wA2, wB2); MVACC(E3, wA3, wB3);
            E0 = F0; E1 = F1; E2 = F2; E3 = F3;
            wA0 = xA0; wB0 = xB0; wA1 = xA1; wB1 = xB1;
            wA2 = xA2; wB2 = xB2; wA3 = xA3; wB3 = xB3;
          }
          MVACC(E0, wA0, wB0); MVACC(E1, wA1, wB1);
          MVACC(E2, wA2, wB2); MVACC(E3, wA3, wB3);
        }
      }
      float4 s0, s1;
      s0.x = (float)a0.x + (float)b0.x; s0.y = (float)a0.y + (float)b0.y;
      s0.z = (float)a1.x + (float)b1.x; s0.w = (float)a1.y + (float)b1.y;
      s1.x = (float)a2.x + (float)b2.x; s1.y = (float)a2.y + (float)b2.y;
      s1.z = (float)a3.x + (float)b3.x; s1.w = (float)a3.y + (float)b3.y;
      float4* pmw = (float4*)(pm[bb] + wv * DH);
      pmw[2 * lane + 0] = s0;
      pmw[2 * lane + 1] = s1;
    }
    prefetch_rows(histd[1], g, g16, t, dj, hA1, hB1);
    __syncthreads();                                     // B0

    float base0 = bh_i + zg0, base1 = bh_i + zg1;
    if (t > 0) {
      float p0 = 0.f, p1 = 0.f;
      #pragma unroll
      for (int sl = 0; sl < 8; ++sl) {
        p0 += pm[0][sl * DH + dim];
        p1 += pm[1][sl * DH + dim];
      }
      base0 += p0; base1 += p1;
    }

    for (int inr = 0; inr <= S_INNER; ++inr) {
      // ---- phase A: x = base + Ah for both batches; DPP sums; lane63 publishes
      float x0, x1;
      {
        float Ah0 = 0.f, Ah1 = 0.f;
        if (inr > 0 && t > 0) {
          Ah0 = compute_ah(hreg0, cbufh2[0], t);
          Ah1 = compute_ah(hreg1, cbufh2[1], t);
        }
        x0 = base0 + Ah0;
        x1 = base1 + Ah1;
        float sa0 = wave64_sum63(x0);
        float sb0 = wave64_sum63(x0 * x0);
        float sa1 = wave64_sum63(x1);
        float sb1 = wave64_sum63(x1 * x1);
        if (lane == 63) {
          red[0][wv] = make_float2(sa0, sb0);
          red[1][wv] = make_float2(sa1, sb1);
        }
      }
      __syncthreads();                                   // B1
      float mu0, rstd0, mu1, rstd1;
      {
        const float4* rr = (const float4*)red[0];
        float4 r0 = rr[0], r1 = rr[1], r2 = rr[2], r3 = rr[3];
        float s  = ((r0.x + r1.x) + (r2.x + r3.x)) + ((r0.z + r1.z) + (r2.z + r3.z));
        float s2 = ((r0.y + r1.y) + (r2.y + r3.y)) + ((r0.w + r1.w) + (r2.w + r3.w));
        const float inv = 1.f / (float)DH;
        mu0 = s * inv;
        rstd0 = rsqrtf(s2 * inv - mu0 * mu0 + 1e-5f);
      }
      {
        const float4* rr = (const float4*)red[1];
        float4 r0 = rr[0], r1 = rr[1], r2 = rr[2], r3 = rr[3];
        float s  = ((r0.x + r1.x) + (r2.x + r3.x)) + ((r0.z + r1.z) + (r2.z + r3.z));
        float s2 = ((r0.y + r1.y) + (r2.y + r3.y)) + ((r0.w + r1.w) + (r2.w + r3.w));
        const float inv = 1.f / (float)DH;
        mu1 = s * inv;
        rstd1 = rsqrtf(s2 * inv - mu1 * mu1 + 1e-5f);
      }

      if (inr < S_INNER) {
        // ---- phase B: LN -> h, publish packed pairs (both batches)
        {
          float h0 = fmaxf(fmaf((x0 - mu0) * rstd0, g_i, be_i), 0.f);
          float h1 = fmaxf(fmaf((x1 - mu1) * rstd1, g_i, be_i), 0.f);
          float hn0 = dpp_mov<0xB1>(h0);
          float hn1 = dpp_mov<0xB1>(h1);
          if (!(dim & 1)) {
            h2cur[0][dim >> 1] = pkh((_Float16)h0, (_Float16)hn0);
            h2cur[1][dim >> 1] = pkh((_Float16)h1, (_Float16)hn1);
          }
        }
        __syncthreads();                                 // B2
        // ---- phase C: dots for both batches
        dot_phase(h2cur[0], hA0, hB0, g16, g, t, dj, lampow, cbufh2[0]);
        dot_phase(h2cur[1], hA1, hB1, g16, g, t, dj, lampow, cbufh2[1]);
        __syncthreads();                                 // B3
      } else {
        // ---- final inner: materialize h, append history, active lists
        {
          float h0 = fmaxf(fmaf((x0 - mu0) * rstd0, g_i, be_i), 0.f);
          float h1 = fmaxf(fmaf((x1 - mu1) * rstd1, g_i, be_i), 0.f);
          unsigned hb0 = (unsigned)__builtin_bit_cast(unsigned short, (_Float16)h0);
          unsigned hb1 = (unsigned)__builtin_bit_cast(unsigned short, (_Float16)h1);
          float hn0 = dpp_mov<0xB1>(h0);
          float hn1 = dpp_mov<0xB1>(h1);
          if (!(dim & 1)) {
            histd[0][t * HDSTRIDE + (dim >> 1)] = pkh((_Float16)h0, (_Float16)hn0);
            histd[1][t * HDSTRIDE + (dim >> 1)] = pkh((_Float16)h1, (_Float16)hn1);
          }
          switch (t) {
            HCASE2(0)  HCASE2(1)  HCASE2(2)  HCASE2(3)  HCASE2(4)  HCASE2(5)
            HCASE2(6)  HCASE2(7)  HCASE2(8)  HCASE2(9)  HCASE2(10) HCASE2(11)
            HCASE2(12) HCASE2(13) HCASE2(14) HCASE2(15) HCASE2(16) HCASE2(17)
            HCASE2(18) HCASE2(19) HCASE2(20) HCASE2(21) HCASE2(22) HCASE2(23)
          }
          if (t == T_STEPS - 1) { hcur[0][dim] = h0; hcur[1][dim] = h1; }
          {
            unsigned long long mb = __ballot(h0 != 0.f);
            int myoff = __popcll(mb & ((1ull << lane) - 1ull));
            int wc  = __popcll(mb);
            int wcp = (wc + 7) & ~7;
            if (h0 != 0.f) {
              _Float16 hh = (_Float16)h0;
              uint2 ent; ent.x = (unsigned)(dim << 10); ent.y = pkh(hh, hh);
              APr[0][wv * 64 + myoff] = ent;
            } else {
              int inact = lane - myoff;
              if (inact < wcp - wc) {
                uint2 zz; zz.x = 0u; zz.y = 0u;
                APr[0][wv * 64 + wc + inact] = zz;
              }
            }
            if (lane == 0) wcntp[0][wv] = wcp;
          }
          {
            unsigned long long mb = __ballot(h1 != 0.f);
            int myoff = __popcll(mb & ((1ull << lane) - 1ull));
            int wc  = __popcll(mb);
            int wcp = (wc + 7) & ~7;
            if (h1 != 0.f) {
              _Float16 hh = (_Float16)h1;
              uint2 ent; ent.x = (unsigned)(dim << 10); ent.y = pkh(hh, hh);
              APr[1][wv * 64 + myoff] = ent;
            } else {
              int inact = lane - myoff;
              if (inact < wcp - wc) {
                uint2 zz; zz.x = 0u; zz.y = 0u;
                APr[1][wv * 64 + wc + inact] = zz;
              }
            }
            if (lane == 0) wcntp[1][wv] = wcp;
          }
        }
        __syncthreads();                                 // B3f
      }
    }
  }

  // ---- epilogue: pred = h @ W_head^T + b_head, then loss/acc (both batches)
  #pragma unroll
  for (int bb = 0; bb < 2; ++bb) {
    for (int r = wv; r < DG; r += 8) {
      const float4* w4  = (const float4*)(W_head + (size_t)r * DH);
      const float4* hc4 = (const float4*)hcur[bb];
      float4 a4 = w4[lane];      float4 c4 = hc4[lane];
      float4 a5 = w4[lane + 64]; float4 c5 = hc4[lane + 64];
      float pdot = a4.x * c4.x + a4.y * c4.y + a4.z * c4.z + a4.w * c4.w
                 + a5.x * c5.x + a5.y * c5.y + a5.z * c5.z + a5.w * c5.w;
      pdot = wave64_sum63(pdot);
      if (lane == 63) pred[bb][r] = pdot + b_head[r];
    }
  }
  __syncthreads();

  #pragma unroll
  for (int bb = 0; bb < 2; ++bb) {
    const int bat = (bb == 0) ? bat0 : bat1;
    float sq = 0.f, pc = 0.f, pp = 0.f, cc = 0.f;
    if (tid < DG) {
      float pv = pred[bb][tid];
      float cv = clean[(size_t)bat * DG + tid];
      float d = pv - cv;
      sq = d * d; pc = pv * cv; pp = pv * pv; cc = cv * cv;
    }
    #pragma unroll
    for (int off = 32; off > 0; off >>= 1) {
      sq += __shfl_xor(sq, off, 64);
      pc += __shfl_xor(pc, off, 64);
      pp += __shfl_xor(pp, off, 64);
      cc += __shfl_xor(cc, off, 64);
    }
    if (lane == 0) {
      red4[bb][wv * 4 + 0] = sq; red4[bb][wv * 4 + 1] = pc;
      red4[bb][wv * 4 + 2] = pp; red4[bb][wv * 4 + 3] = cc;
    }
  }
  __syncthreads();
  if (tid < 2) {
    const int bat = (tid == 0) ? bat0 : bat1;
    float Sq = 0.f, Pc = 0.f, Pp = 0.f, Cc = 0.f;
    #pragma unroll
    for (int w = 0; w < 8; ++w) {
      Sq += red4[tid][w * 4 + 0]; Pc += red4[tid][w * 4 + 1];
      Pp += red4[tid][w * 4 + 2]; Cc += red4[tid][w * 4 + 3];
    }
    outbuf[bat]         = Sq / (Cc + 1e-6f);
    outbuf[BATCH + bat] = Pc / ((sqrtf(Pp) + 1e-6f) * (sqrtf(Cc) + 1e-6f));
  }
}

__global__ __launch_bounds__(64)
void finalize_k(const float* __restrict__ outbuf, float* __restrict__ out) {
  int tid = threadIdx.x;
  float l = (tid < BATCH) ? outbuf[tid] : 0.f;
  float a = (tid < BATCH) ? outbuf[BATCH + tid] : 0.f;
  #pragma unroll
  for (int off = 32; off > 0; off >>= 1) {
    l += __shfl_xor(l, off, 64);
    a += __shfl_xor(a, off, 64);
  }
  if (tid == 0) {
    out[0] = l * (1.f / (float)BATCH);
    out[1] = a * (1.f / (float)BATCH);
  }
}

extern "C" void kernel_launch(void* const* d_in, const int* in_sizes, int n_in,
                              void* d_out, int out_size, void* d_ws, size_t ws_size,
                              hipStream_t stream) {
  (void)in_sizes; (void)n_in; (void)out_size; (void)ws_size;
  const float* z      = (const float*)d_in[0];
  const float* clean  = (const float*)d_in[1];
  const float* W_h    = (const float*)d_in[2];
  const float* W_g    = (const float*)d_in[3];
  const float* b_h    = (const float*)d_in[4];
  const float* gamma  = (const float*)d_in[5];
  const float* beta   = (const float*)d_in[6];
  const float* W_head = (const float*)d_in[7];
  const float* b_head = (const float*)d_in[8];

  float* wsf     = (float*)d_ws;
  uint2* Whq     = (uint2*)wsf;                           // 65536 uint2
  float* WgT     = wsf + 131072;                          // 256*512
  float* ZG      = WgT + (size_t)DG * DH;                 // 2304*512
  float* outbuf  = ZG + (size_t)T_STEPS * BATCH * DH;     // 96

  hipLaunchKernelGGL(pack_whq, dim3(256), dim3(256), 0, stream, W_h, Whq);
  hipLaunchKernelGGL(transpose_k, dim3(DG / 32, DH / 32), dim3(256), 0, stream,
                     W_g, WgT, DH, DG);
  hipLaunchKernelGGL(zg_kernel, dim3((T_STEPS * BATCH) / 8), dim3(DH), 0, stream,
                     z, WgT, ZG);
  hipLaunchKernelGGL(rnn_main, dim3(BATCH / 2), dim3(512), 0, stream,
                     ZG, Whq, b_h, gamma, beta, W_head, b_head, clean, outbuf);
  hipLaunchKernelGGL(finalize_k, dim3(1), dim3(64), 0, stream,
                     outbuf, (float*)d_out);
}

// Round 14
// 590.170 us; speedup vs baseline: 1.0071x; 1.0069x over previous
//
#include <hip/hip_runtime.h>

#define T_STEPS 48
#define BATCH   48
#define DG      256
#define DH      512
#define S_INNER 3
#define HDSTRIDE 260   // histd row stride in u32: +4-bank skew per row, 16B-aligned

typedef _Float16 hf2 __attribute__((ext_vector_type(2)));

__device__ __forceinline__ hf2 bch(unsigned u) { return __builtin_bit_cast(hf2, u); }
__device__ __forceinline__ unsigned pkh(_Float16 a, _Float16 b) {
  hf2 v{a, b}; return __builtin_bit_cast(unsigned, v);
}
__device__ __forceinline__ float fdot2u(unsigned a, unsigned b, float c) {
#if __has_builtin(__builtin_amdgcn_fdot2)
  return __builtin_amdgcn_fdot2(bch(a), bch(b), c, false);
#else
  hf2 x = bch(a), y = bch(b);
  return fmaf((float)x.x, (float)y.x, fmaf((float)x.y, (float)y.y, c));
#endif
}
template <int CTRL>
__device__ __forceinline__ float dpp_add(float v) {
  int t = __builtin_amdgcn_update_dpp(0, __float_as_int(v), CTRL, 0xf, 0xf, true);
  return v + __int_as_float(t);
}
template <int CTRL>
__device__ __forceinline__ float dpp_mov(float v) {
  return __int_as_float(
      __builtin_amdgcn_update_dpp(0, __float_as_int(v), CTRL, 0xf, 0xf, true));
}
// 64-lane sum, result valid in lane 63; zero LDS traffic
__device__ __forceinline__ float wave64_sum63(float v) {
  v = dpp_add<0xB1>(v);    // xor1 (quad_perm)
  v = dpp_add<0x4E>(v);    // xor2 (quad_perm)
  v = dpp_add<0x141>(v);   // row_half_mirror
  v = dpp_add<0x140>(v);   // row_mirror
  v = dpp_add<0x142>(v);   // row_bcast15
  v = dpp_add<0x143>(v);   // row_bcast31 -> total in lane 63
  return v;
}
// sum over each 16-lane row, result in all 16 lanes of the row
__device__ __forceinline__ float row16_sum(float v) {
  v = dpp_add<0xB1>(v);
  v = dpp_add<0x4E>(v);
  v = dpp_add<0x141>(v);
  v = dpp_add<0x140>(v);
  return v;
}

// ---------- weight packing: Whq[j*128 + q] = 4 dims {4q..4q+3} of column j, fp16
__global__ __launch_bounds__(256)
void pack_whq(const float* __restrict__ W, uint2* __restrict__ Wq) {
  int idx = blockIdx.x * 256 + threadIdx.x;   // 65536
  int j = idx & (DH - 1), q = idx >> 9;
  float w0 = W[(size_t)(4 * q + 0) * DH + j];
  float w1 = W[(size_t)(4 * q + 1) * DH + j];
  float w2 = W[(size_t)(4 * q + 2) * DH + j];
  float w3 = W[(size_t)(4 * q + 3) * DH + j];
  uint2 o;
  o.x = pkh((_Float16)w0, (_Float16)w1);
  o.y = pkh((_Float16)w2, (_Float16)w3);
  Wq[(size_t)j * 128 + q] = o;
}

__global__ __launch_bounds__(256)
void transpose_k(const float* __restrict__ in, float* __restrict__ out, int R, int C) {
  __shared__ float tile[32][33];
  int c0 = blockIdx.x * 32, r0 = blockIdx.y * 32;
  int tx = threadIdx.x & 31, ty = threadIdx.x >> 5;
  #pragma unroll
  for (int k = 0; k < 32; k += 8)
    tile[ty + k][tx] = in[(size_t)(r0 + ty + k) * C + (c0 + tx)];
  __syncthreads();
  #pragma unroll
  for (int k = 0; k < 32; k += 8)
    out[(size_t)(c0 + ty + k) * R + (r0 + tx)] = tile[tx][ty + k];
}

__global__ __launch_bounds__(DH, 2)
void zg_kernel(const float* __restrict__ z, const float* __restrict__ WgT,
               float* __restrict__ ZG) {
  const int row0 = blockIdx.x * 8;
  const int tid = threadIdx.x;
  __shared__ __align__(16) float zl[8][DG];
  for (int i = tid; i < 8 * (DG / 4); i += DH) {
    int r = i >> 6, c = i & 63;
    ((float4*)zl[r])[c] = ((const float4*)(z + (size_t)(row0 + r) * DG))[c];
  }
  __syncthreads();
  float acc[8] = {0.f, 0.f, 0.f, 0.f, 0.f, 0.f, 0.f, 0.f};
  for (int j = 0; j < DG; j += 4) {
    float w0 = WgT[(size_t)(j + 0) * DH + tid];
    float w1 = WgT[(size_t)(j + 1) * DH + tid];
    float w2 = WgT[(size_t)(j + 2) * DH + tid];
    float w3 = WgT[(size_t)(j + 3) * DH + tid];
    #pragma unroll
    for (int r = 0; r < 8; ++r) {
      float4 zz = ((const float4*)zl[r])[j >> 2];
      acc[r] = fmaf(w0, zz.x, acc[r]);
      acc[r] = fmaf(w1, zz.y, acc[r]);
      acc[r] = fmaf(w2, zz.z, acc[r]);
      acc[r] = fmaf(w3, zz.w, acc[r]);
    }
  }
  #pragma unroll
  for (int r = 0; r < 8; ++r)
    ZG[(size_t)(row0 + r) * DH + tid] = acc[r];
}

#define HCASE2(s) \
  case (2*(s)):   hreg0[(s)] = hb0;          hreg1[(s)] = hb1;          break; \
  case (2*(s)+1): hreg0[(s)] |= (hb0 << 16); hreg1[(s)] |= (hb1 << 16); break;

#define MVACC(E, wA, wB) do {                                        \
    hf2 h0 = bch((E).y), h1 = bch((E).w);                            \
    a0 += bch((wA).x) * h0; a1 += bch((wA).y) * h0;                  \
    a2 += bch((wA).z) * h0; a3 += bch((wA).w) * h0;                  \
    b0 += bch((wB).x) * h1; b1 += bch((wB).y) * h1;                  \
    b2 += bch((wB).z) * h1; b3 += bch((wB).w) * h1;                  \
  } while (0)

#define LDW(off) (*(const uint4*)(Wb + ((off) + l16)))

// Ah for one batch: hreg . cbuf, gated by t
__device__ __forceinline__ float compute_ah(const unsigned (&hreg)[24],
                                            const unsigned* cbuf, int t) {
  const uint4* cbp = (const uint4*)cbuf;
  float A0 = 0.f, A1 = 0.f, A2 = 0.f, A3 = 0.f;
  {
    uint4 c = cbp[0];
    A0 = fdot2u(hreg[0], c.x, A0); A1 = fdot2u(hreg[1], c.y, A1);
    A2 = fdot2u(hreg[2], c.z, A2); A3 = fdot2u(hreg[3], c.w, A3);
  }
  if (t > 8) {
    uint4 c = cbp[1];
    A0 = fdot2u(hreg[4], c.x, A0); A1 = fdot2u(hreg[5], c.y, A1);
    A2 = fdot2u(hreg[6], c.z, A2); A3 = fdot2u(hreg[7], c.w, A3);
  }
  if (t > 16) {
    uint4 c = cbp[2];
    A0 = fdot2u(hreg[8], c.x, A0);  A1 = fdot2u(hreg[9], c.y, A1);
    A2 = fdot2u(hreg[10], c.z, A2); A3 = fdot2u(hreg[11], c.w, A3);
  }
  if (t > 24) {
    uint4 c = cbp[3];
    A0 = fdot2u(hreg[12], c.x, A0); A1 = fdot2u(hreg[13], c.y, A1);
    A2 = fdot2u(hreg[14], c.z, A2); A3 = fdot2u(hreg[15], c.w, A3);
  }
  if (t > 32) {
    uint4 c = cbp[4];
    A0 = fdot2u(hreg[16], c.x, A0); A1 = fdot2u(hreg[17], c.y, A1);
    A2 = fdot2u(hreg[18], c.z, A2); A3 = fdot2u(hreg[19], c.w, A3);
  }
  if (t > 40) {
    uint4 c = cbp[5];
    A0 = fdot2u(hreg[20], c.x, A0); A1 = fdot2u(hreg[21], c.y, A1);
    A2 = fdot2u(hreg[22], c.z, A2); A3 = fdot2u(hreg[23], c.w, A3);
  }
  return (A0 + A1) + (A2 + A3);
}

__device__ __forceinline__ void prefetch_rows(const unsigned* hist, int g, bool g16,
                                              int t, int dj,
                                              uint4 (&hA)[4], uint4 (&hB)[4]) {
  #pragma unroll
  for (int k = 0; k < 4; ++k) {
    hA[k] = make_uint4(0u, 0u, 0u, 0u);
    hB[k] = make_uint4(0u, 0u, 0u, 0u);
  }
  if (g < t) {
    const unsigned* rp = hist + g * HDSTRIDE + 4 * dj;
    hA[0] = *(const uint4*)(rp + 0);
    hA[1] = *(const uint4*)(rp + 64);
    hA[2] = *(const uint4*)(rp + 128);
    hA[3] = *(const uint4*)(rp + 192);
  }
  if (g16 && 32 + g < t) {
    const unsigned* rp = hist + (32 + g) * HDSTRIDE + 4 * dj;
    hB[0] = *(const uint4*)(rp + 0);
    hB[1] = *(const uint4*)(rp + 64);
    hB[2] = *(const uint4*)(rp + 128);
    hB[3] = *(const uint4*)(rp + 192);
  }
}

// dot phase for one batch: rows g (and 32+g), write c coeffs
__device__ __forceinline__ void dot_phase(const unsigned* h2c,
                                          const uint4 (&hA)[4], const uint4 (&hB)[4],
                                          bool g16, int g, int t, int dj,
                                          const float* lampow, unsigned* cbuf) {
  float pA = 0.f, pB = 0.f;
  if (g < t) {
    const unsigned* hp = h2c + 4 * dj;
    uint4 v0 = *(const uint4*)(hp + 0);
    uint4 v1 = *(const uint4*)(hp + 64);
    uint4 v2 = *(const uint4*)(hp + 128);
    uint4 v3 = *(const uint4*)(hp + 192);
    float a0 = 0.f, a1 = 0.f, a2 = 0.f, a3 = 0.f;
    a0 = fdot2u(hA[0].x, v0.x, a0); a1 = fdot2u(hA[0].y, v0.y, a1);
    a2 = fdot2u(hA[0].z, v0.z, a2); a3 = fdot2u(hA[0].w, v0.w, a3);
    a0 = fdot2u(hA[1].x, v1.x, a0); a1 = fdot2u(hA[1].y, v1.y, a1);
    a2 = fdot2u(hA[1].z, v1.z, a2); a3 = fdot2u(hA[1].w, v1.w, a3);
    a0 = fdot2u(hA[2].x, v2.x, a0); a1 = fdot2u(hA[2].y, v2.y, a1);
    a2 = fdot2u(hA[2].z, v2.z, a2); a3 = fdot2u(hA[2].w, v2.w, a3);
    a0 = fdot2u(hA[3].x, v3.x, a0); a1 = fdot2u(hA[3].y, v3.y, a1);
    a2 = fdot2u(hA[3].z, v3.z, a2); a3 = fdot2u(hA[3].w, v3.w, a3);
    pA = row16_sum((a0 + a1) + (a2 + a3));
    if (g16 && 32 + g < t) {
      float e0 = 0.f, e1 = 0.f, e2 = 0.f, e3 = 0.f;
      e0 = fdot2u(hB[0].x, v0.x, e0); e1 = fdot2u(hB[0].y, v0.y, e1);
      e2 = fdot2u(hB[0].z, v0.z, e2); e3 = fdot2u(hB[0].w, v0.w, e3);
      e0 = fdot2u(hB[1].x, v1.x, e0); e1 = fdot2u(hB[1].y, v1.y, e1);
      e2 = fdot2u(hB[1].z, v1.z, e2); e3 = fdot2u(hB[1].w, v1.w, e3);
      e0 = fdot2u(hB[2].x, v2.x, e0); e1 = fdot2u(hB[2].y, v2.y, e1);
      e2 = fdot2u(hB[2].z, v2.z, e2); e3 = fdot2u(hB[2].w, v2.w, e3);
      e0 = fdot2u(hB[3].x, v3.x, e0); e1 = fdot2u(hB[3].y, v3.y, e1);
      e2 = fdot2u(hB[3].z, v3.z, e2); e3 = fdot2u(hB[3].w, v3.w, e3);
      pB = row16_sum((e0 + e1) + (e2 + e3));
    }
  }
  if (dj == 0) {
    float ccA = (g < t) ? pA * lampow[t - 1 - g] : 0.f;
    _Float16 chA = (_Float16)ccA;
    ((unsigned short*)cbuf)[g] = __builtin_bit_cast(unsigned short, chA);
    if (g16) {
      int rB = 32 + g;
      float ccB = (rB < t) ? pB * lampow[t - 1 - rB] : 0.f;
      _Float16 chB = (_Float16)ccB;
      ((unsigned short*)cbuf)[rB] = __builtin_bit_cast(unsigned short, chB);
    }
  }
}

__global__ __launch_bounds__(512)
__attribute__((amdgpu_waves_per_eu(2, 2)))
void rnn_main(const float* __restrict__ ZG, const uint2* __restrict__ Whq,
              const float* __restrict__ bh, const float* __restrict__ gamma,
              const float* __restrict__ beta, const float* __restrict__ W_head,
              const float* __restrict__ b_head, const float* __restrict__ clean,
              float* __restrict__ outbuf) {
  const int bat0 = blockIdx.x * 2, bat1 = bat0 + 1;
  const int tid  = threadIdx.x;         // 512 threads = 8 waves, 2 batches
  const int lane = tid & 63;
  const int wv   = tid >> 6;            // wave = matvec slice = active region
  const int dim  = tid;                 // owner dim
  const int g    = tid >> 4;            // dot group 0..31
  const int dj   = tid & 15;            // chunk id within row
  const bool g16 = tid < 256;           // groups 0..15 take rows g and 32+g

  __shared__ __align__(16) unsigned histd[2][T_STEPS * HDSTRIDE];  // ~99.8KB
  __shared__ __align__(16) float    pm[2][8 * DH];                 // 32KB
  __shared__ __align__(16) uint2    APr[2][8 * 64];                // 8KB
  __shared__ __align__(16) unsigned h2cur[2][256];                 // 2KB
  __shared__ __align__(16) unsigned cbufh2[2][32];                 // 256B
  __shared__ __align__(16) float    hcur[2][DH];                   // 4KB
  __shared__ __align__(16) float    pred[2][DG];                   // 2KB
  __shared__ __align__(16) float2   red[2][8];
  __shared__ float  red4[2][32];
  __shared__ int    wcntp[2][8];
  __shared__ float  lampow[T_STEPS];

  const float g_i  = gamma[dim];
  const float be_i = beta[dim];
  const float bh_i = bh[dim];
  if (tid == 0) {
    float pw = 0.5f;                    // eta folded in
    for (int k = 0; k < T_STEPS; ++k) { lampow[k] = pw; pw *= 0.95f; }
  }
  unsigned hreg0[24], hreg1[24];        // owner's fp16 history columns
  #pragma unroll
  for (int k = 0; k < 24; ++k) { hreg0[k] = 0u; hreg1[k] = 0u; }

  const char* Wb = (const char*)Whq;    // SGPR base for saddr-form gathers
  const unsigned l16 = (unsigned)(lane << 4);
  __syncthreads();

  for (int t = 0; t < T_STEPS; ++t) {
    float zg0 = ZG[((size_t)t * BATCH + bat0) * DH + dim];
    float zg1 = ZG[((size_t)t * BATCH + bat1) * DH + dim];

    // ---- matvec for both batches (sequential, each 4-deep pipelined)
    #pragma unroll
    for (int bb = 0; bb < 2; ++bb) {
      hf2 a0{}, a1{}, a2{}, a3{}, b0{}, b1{}, b2{}, b3{};
      if (t > 0) {
        const int n = wcntp[bb][wv];    // multiple of 8 (or 0), uniform in wave
        if (n > 0) {
          const uint4* ap4 = (const uint4*)(APr[bb] + wv * 64);
          const int G = n >> 1;          // multiple of 4, >= 4
          uint4 E0 = ap4[0], E1 = ap4[1], E2 = ap4[2], E3 = ap4[3];
          uint4 wA0 = LDW(E0.x), wB0 = LDW(E0.z);
          uint4 wA1 = LDW(E1.x), wB1 = LDW(E1.z);
          uint4 wA2 = LDW(E2.x), wB2 = LDW(E2.z);
          uint4 wA3 = LDW(E3.x), wB3 = LDW(E3.z);
          for (int grp = 4; grp < G; grp += 4) {
            uint4 F0 = ap4[grp], F1 = ap4[grp + 1];
            uint4 F2 = ap4[grp + 2], F3 = ap4[grp + 3];
            uint4 xA0 = LDW(F0.x), xB0 = LDW(F0.z);
            uint4 xA1 = LDW(F1.x), xB1 = LDW(F1.z);
            uint4 xA2 = LDW(F2.x), xB2 = LDW(F2.z);
            uint4 xA3 = LDW(F3.x), xB3 = LDW(F3.z);
            MVACC(E0, wA0, wB0); MVACC(E1, wA1, wB1);
            MVACC(E2, wA2, wB2); MVACC(E3, wA3, wB3);
            E0 = F0; E1 = F1; E2 = F2; E3 = F3;
            wA0 = xA0; wB0 = xB0; wA1 = xA1; wB1 = xB1;
            wA2 = xA2; wB2 = xB2; wA3 = xA3; wB3 = xB3;
          }
          MVACC(E0, wA0, wB0); MVACC(E1, wA1, wB1);
          MVACC(E2, wA2, wB2); MVACC(E3, wA3, wB3);
        }
      }
      float4 s0, s1;
      s0.x = (float)a0.x + (float)b0.x; s0.y = (float)a0.y + (float)b0.y;
      s0.z = (float)a1.x + (float)b1.x; s0.w = (float)a1.y + (float)b1.y;
      s1.x = (float)a2.x + (float)b2.x; s1.y = (float)a2.y + (float)b2.y;
      s1.z = (float)a3.x + (float)b3.x; s1.w = (float)a3.y + (float)b3.y;
      float4* pmw = (float4*)(pm[bb] + wv * DH);
      pmw[2 * lane + 0] = s0;
      pmw[2 * lane + 1] = s1;
    }

    // per-step dot-row prefetch AFTER matvec (minimizes live-range overlap)
    uint4 hA0[4], hB0[4], hA1[4], hB1[4];
    prefetch_rows(histd[0], g, g16, t, dj, hA0, hB0);
    prefetch_rows(histd[1], g, g16, t, dj, hA1, hB1);
    __syncthreads();                                     // B0

    float base0 = bh_i + zg0, base1 = bh_i + zg1;
    if (t > 0) {
      float p0 = 0.f, p1 = 0.f;
      #pragma unroll
      for (int sl = 0; sl < 8; ++sl) {
        p0 += pm[0][sl * DH + dim];
        p1 += pm[1][sl * DH + dim];
      }
      base0 += p0; base1 += p1;
    }

    for (int inr = 0; inr <= S_INNER; ++inr) {
      // ---- phase A: x = base + Ah for both batches; DPP sums; lane63 publishes
      float x0, x1;
      {
        float Ah0 = 0.f, Ah1 = 0.f;
        if (inr > 0 && t > 0) {
          Ah0 = compute_ah(hreg0, cbufh2[0], t);
          Ah1 = compute_ah(hreg1, cbufh2[1], t);
        }
        x0 = base0 + Ah0;
        x1 = base1 + Ah1;
        float sa0 = wave64_sum63(x0);
        float sb0 = wave64_sum63(x0 * x0);
        float sa1 = wave64_sum63(x1);
        float sb1 = wave64_sum63(x1 * x1);
        if (lane == 63) {
          red[0][wv] = make_float2(sa0, sb0);
          red[1][wv] = make_float2(sa1, sb1);
        }
      }
      __syncthreads();                                   // B1
      float mu0, rstd0, mu1, rstd1;
      {
        const float4* rr = (const float4*)red[0];
        float4 r0 = rr[0], r1 = rr[1], r2 = rr[2], r3 = rr[3];
        float s  = ((r0.x + r1.x) + (r2.x + r3.x)) + ((r0.z + r1.z) + (r2.z + r3.z));
        float s2 = ((r0.y + r1.y) + (r2.y + r3.y)) + ((r0.w + r1.w) + (r2.w + r3.w));
        const float inv = 1.f / (float)DH;
        mu0 = s * inv;
        rstd0 = rsqrtf(s2 * inv - mu0 * mu0 + 1e-5f);
      }
      {
        const float4* rr = (const float4*)red[1];
        float4 r0 = rr[0], r1 = rr[1], r2 = rr[2], r3 = rr[3];
        float s  = ((r0.x + r1.x) + (r2.x + r3.x)) + ((r0.z + r1.z) + (r2.z + r3.z));
        float s2 = ((r0.y + r1.y) + (r2.y + r3.y)) + ((r0.w + r1.w) + (r2.w + r3.w));
        const float inv = 1.f / (float)DH;
        mu1 = s * inv;
        rstd1 = rsqrtf(s2 * inv - mu1 * mu1 + 1e-5f);
      }

      if (inr < S_INNER) {
        // ---- phase B: LN -> h, publish packed pairs (both batches)
        {
          float h0 = fmaxf(fmaf((x0 - mu0) * rstd0, g_i, be_i), 0.f);
          float h1 = fmaxf(fmaf((x1 - mu1) * rstd1, g_i, be_i), 0.f);
          float hn0 = dpp_mov<0xB1>(h0);
          float hn1 = dpp_mov<0xB1>(h1);
          if (!(dim & 1)) {
            h2cur[0][dim >> 1] = pkh((_Float16)h0, (_Float16)hn0);
            h2cur[1][dim >> 1] = pkh((_Float16)h1, (_Float16)hn1);
          }
        }
        __syncthreads();                                 // B2
        // ---- phase C: dots for both batches
        dot_phase(h2cur[0], hA0, hB0, g16, g, t, dj, lampow, cbufh2[0]);
        dot_phase(h2cur[1], hA1, hB1, g16, g, t, dj, lampow, cbufh2[1]);
        __syncthreads();                                 // B3
      } else {
        // ---- final inner: materialize h, append history, active lists
        {
          float h0 = fmaxf(fmaf((x0 - mu0) * rstd0, g_i, be_i), 0.f);
          float h1 = fmaxf(fmaf((x1 - mu1) * rstd1, g_i, be_i), 0.f);
          unsigned hb0 = (unsigned)__builtin_bit_cast(unsigned short, (_Float16)h0);
          unsigned hb1 = (unsigned)__builtin_bit_cast(unsigned short, (_Float16)h1);
          float hn0 = dpp_mov<0xB1>(h0);
          float hn1 = dpp_mov<0xB1>(h1);
          if (!(dim & 1)) {
            histd[0][t * HDSTRIDE + (dim >> 1)] = pkh((_Float16)h0, (_Float16)hn0);
            histd[1][t * HDSTRIDE + (dim >> 1)] = pkh((_Float16)h1, (_Float16)hn1);
          }
          switch (t) {
            HCASE2(0)  HCASE2(1)  HCASE2(2)  HCASE2(3)  HCASE2(4)  HCASE2(5)
            HCASE2(6)  HCASE2(7)  HCASE2(8)  HCASE2(9)  HCASE2(10) HCASE2(11)
            HCASE2(12) HCASE2(13) HCASE2(14) HCASE2(15) HCASE2(16) HCASE2(17)
            HCASE2(18) HCASE2(19) HCASE2(20) HCASE2(21) HCASE2(22) HCASE2(23)
          }
          if (t == T_STEPS - 1) { hcur[0][dim] = h0; hcur[1][dim] = h1; }
          {
            unsigned long long mb = __ballot(h0 != 0.f);
            int myoff = __popcll(mb & ((1ull << lane) - 1ull));
            int wc  = __popcll(mb);
            int wcp = (wc + 7) & ~7;
            if (h0 != 0.f) {
              _Float16 hh = (_Float16)h0;
              uint2 ent; ent.x = (unsigned)(dim << 10); ent.y = pkh(hh, hh);
              APr[0][wv * 64 + myoff] = ent;
            } else {
              int inact = lane - myoff;
              if (inact < wcp - wc) {
                uint2 zz; zz.x = 0u; zz.y = 0u;
                APr[0][wv * 64 + wc + inact] = zz;
              }
            }
            if (lane == 0) wcntp[0][wv] = wcp;
          }
          {
            unsigned long long mb = __ballot(h1 != 0.f);
            int myoff = __popcll(mb & ((1ull << lane) - 1ull));
            int wc  = __popcll(mb);
            int wcp = (wc + 7) & ~7;
            if (h1 != 0.f) {
              _Float16 hh = (_Float16)h1;
              uint2 ent; ent.x = (unsigned)(dim << 10); ent.y = pkh(hh, hh);
              APr[1][wv * 64 + myoff] = ent;
            } else {
              int inact = lane - myoff;
              if (inact < wcp - wc) {
                uint2 zz; zz.x = 0u; zz.y = 0u;
                APr[1][wv * 64 + wc + inact] = zz;
              }
            }
            if (lane == 0) wcntp[1][wv] = wcp;
          }
        }
        __syncthreads();                                 // B3f
      }
    }
  }

  // ---- epilogue: pred = h @ W_head^T + b_head, then loss/acc (both batches)
  #pragma unroll
  for (int bb = 0; bb < 2; ++bb) {
    for (int r = wv; r < DG; r += 8) {
      const float4* w4  = (const float4*)(W_head + (size_t)r * DH);
      const float4* hc4 = (const float4*)hcur[bb];
      float4 a4 = w4[lane];      float4 c4 = hc4[lane];
      float4 a5 = w4[lane + 64]; float4 c5 = hc4[lane + 64];
      float pdot = a4.x * c4.x + a4.y * c4.y + a4.z * c4.z + a4.w * c4.w
                 + a5.x * c5.x + a5.y * c5.y + a5.z * c5.z + a5.w * c5.w;
      pdot = wave64_sum63(pdot);
      if (lane == 63) pred[bb][r] = pdot + b_head[r];
    }
  }
  __syncthreads();

  #pragma unroll
  for (int bb = 0; bb < 2; ++bb) {
    const int bat = (bb == 0) ? bat0 : bat1;
    float sq = 0.f, pc = 0.f, pp = 0.f, cc = 0.f;
    if (tid < DG) {
      float pv = pred[bb][tid];
      float cv = clean[(size_t)bat * DG + tid];
      float d = pv - cv;
      sq = d * d; pc = pv * cv; pp = pv * pv; cc = cv * cv;
    }
    #pragma unroll
    for (int off = 32; off > 0; off >>= 1) {
      sq += __shfl_xor(sq, off, 64);
      pc += __shfl_xor(pc, off, 64);
      pp += __shfl_xor(pp, off, 64);
      cc += __shfl_xor(cc, off, 64);
    }
    if (lane == 0) {
      red4[bb][wv * 4 + 0] = sq; red4[bb][wv * 4 + 1] = pc;
      red4[bb][wv * 4 + 2] = pp; red4[bb][wv * 4 + 3] = cc;
    }
  }
  __syncthreads();
  if (tid < 2) {
    const int bat = (tid == 0) ? bat0 : bat1;
    float Sq = 0.f, Pc = 0.f, Pp = 0.f, Cc = 0.f;
    #pragma unroll
    for (int w = 0; w < 8; ++w) {
      Sq += red4[tid][w * 4 + 0]; Pc += red4[tid][w * 4 + 1];
      Pp += red4[tid][w * 4 + 2]; Cc += red4[tid][w * 4 + 3];
    }
    outbuf[bat]         = Sq / (Cc + 1e-6f);
    outbuf[BATCH + bat] = Pc / ((sqrtf(Pp) + 1e-6f) * (sqrtf(Cc) + 1e-6f));
  }
}

__global__ __launch_bounds__(64)
void finalize_k(const float* __restrict__ outbuf, float* __restrict__ out) {
  int tid = threadIdx.x;
  float l = (tid < BATCH) ? outbuf[tid] : 0.f;
  float a = (tid < BATCH) ? outbuf[BATCH + tid] : 0.f;
  #pragma unroll
  for (int off = 32; off > 0; off >>= 1) {
    l += __shfl_xor(l, off, 64);
    a += __shfl_xor(a, off, 64);
  }
  if (tid == 0) {
    out[0] = l * (1.f / (float)BATCH);
    out[1] = a * (1.f / (float)BATCH);
  }
}

extern "C" void kernel_launch(void* const* d_in, const int* in_sizes, int n_in,
                              void* d_out, int out_size, void* d_ws, size_t ws_size,
                              hipStream_t stream) {
  (void)in_sizes; (void)n_in; (void)out_size; (void)ws_size;
  const float* z      = (const float*)d_in[0];
  const float* clean  = (const float*)d_in[1];
  const float* W_h    = (const float*)d_in[2];
  const float* W_g    = (const float*)d_in[3];
  const float* b_h    = (const float*)d_in[4];
  const float* gamma  = (const float*)d_in[5];
  const float* beta   = (const float*)d_in[6];
  const float* W_head = (const float*)d_in[7];
  const float* b_head = (const float*)d_in[8];

  float* wsf     = (float*)d_ws;
  uint2* Whq     = (uint2*)wsf;                           // 65536 uint2
  float* WgT     = wsf + 131072;                          // 256*512
  float* ZG      = WgT + (size_t)DG * DH;                 // 2304*512
  float* outbuf  = ZG + (size_t)T_STEPS * BATCH * DH;     // 96

  hipLaunchKernelGGL(pack_whq, dim3(256), dim3(256), 0, stream, W_h, Whq);
  hipLaunchKernelGGL(transpose_k, dim3(DG / 32, DH / 32), dim3(256), 0, stream,
                     W_g, WgT, DH, DG);
  hipLaunchKernelGGL(zg_kernel, dim3((T_STEPS * BATCH) / 8), dim3(DH), 0, stream,
                     z, WgT, ZG);
  hipLaunchKernelGGL(rnn_main, dim3(BATCH / 2), dim3(512), 0, stream,
                     ZG, Whq, b_h, gamma, beta, W_head, b_head, clean, outbuf);
  hipLaunchKernelGGL(finalize_k, dim3(1), dim3(64), 0, stream,
                     outbuf, (float*)d_out);
}

// Round 15
// 278.480 us; speedup vs baseline: 2.1343x; 2.1193x over previous
//
#include <hip/hip_runtime.h>

#define T_STEPS 48
#define BATCH   48
#define DG      256
#define DH      512
#define S_INNER 3
#define HDSTRIDE 260   // histd row stride in u32: +4-bank skew per row, 16B-aligned

typedef _Float16 hf2 __attribute__((ext_vector_type(2)));

__device__ __forceinline__ hf2 bch(unsigned u) { return __builtin_bit_cast(hf2, u); }
__device__ __forceinline__ unsigned pkh(_Float16 a, _Float16 b) {
  hf2 v{a, b}; return __builtin_bit_cast(unsigned, v);
}
__device__ __forceinline__ float fdot2u(unsigned a, unsigned b, float c) {
#if __has_builtin(__builtin_amdgcn_fdot2)
  return __builtin_amdgcn_fdot2(bch(a), bch(b), c, false);
#else
  hf2 x = bch(a), y = bch(b);
  return fmaf((float)x.x, (float)y.x, fmaf((float)x.y, (float)y.y, c));
#endif
}
template <int CTRL>
__device__ __forceinline__ float dpp_add(float v) {
  int t = __builtin_amdgcn_update_dpp(0, __float_as_int(v), CTRL, 0xf, 0xf, true);
  return v + __int_as_float(t);
}
template <int CTRL>
__device__ __forceinline__ float dpp_mov(float v) {
  return __int_as_float(
      __builtin_amdgcn_update_dpp(0, __float_as_int(v), CTRL, 0xf, 0xf, true));
}
// 64-lane sum, result valid in lane 63; zero LDS traffic
__device__ __forceinline__ float wave64_sum63(float v) {
  v = dpp_add<0xB1>(v);    // xor1 (quad_perm)
  v = dpp_add<0x4E>(v);    // xor2 (quad_perm)
  v = dpp_add<0x141>(v);   // row_half_mirror
  v = dpp_add<0x140>(v);   // row_mirror
  v = dpp_add<0x142>(v);   // row_bcast15
  v = dpp_add<0x143>(v);   // row_bcast31 -> total in lane 63
  return v;
}
// sum over each 16-lane row, result in all 16 lanes of the row
__device__ __forceinline__ float row16_sum(float v) {
  v = dpp_add<0xB1>(v);
  v = dpp_add<0x4E>(v);
  v = dpp_add<0x141>(v);
  v = dpp_add<0x140>(v);
  return v;
}

// ---------- weight packing: Whq[j*128 + q] = 4 dims {4q..4q+3} of column j, fp16
__global__ __launch_bounds__(256)
void pack_whq(const float* __restrict__ W, uint2* __restrict__ Wq) {
  int idx = blockIdx.x * 256 + threadIdx.x;   // 65536
  int j = idx & (DH - 1), q = idx >> 9;
  float w0 = W[(size_t)(4 * q + 0) * DH + j];
  float w1 = W[(size_t)(4 * q + 1) * DH + j];
  float w2 = W[(size_t)(4 * q + 2) * DH + j];
  float w3 = W[(size_t)(4 * q + 3) * DH + j];
  uint2 o;
  o.x = pkh((_Float16)w0, (_Float16)w1);
  o.y = pkh((_Float16)w2, (_Float16)w3);
  Wq[(size_t)j * 128 + q] = o;
}

__global__ __launch_bounds__(256)
void transpose_k(const float* __restrict__ in, float* __restrict__ out, int R, int C) {
  __shared__ float tile[32][33];
  int c0 = blockIdx.x * 32, r0 = blockIdx.y * 32;
  int tx = threadIdx.x & 31, ty = threadIdx.x >> 5;
  #pragma unroll
  for (int k = 0; k < 32; k += 8)
    tile[ty + k][tx] = in[(size_t)(r0 + ty + k) * C + (c0 + tx)];
  __syncthreads();
  #pragma unroll
  for (int k = 0; k < 32; k += 8)
    out[(size_t)(c0 + ty + k) * R + (r0 + tx)] = tile[tx][ty + k];
}

__global__ __launch_bounds__(DH, 2)
void zg_kernel(const float* __restrict__ z, const float* __restrict__ WgT,
               float* __restrict__ ZG) {
  const int row0 = blockIdx.x * 8;
  const int tid = threadIdx.x;
  __shared__ __align__(16) float zl[8][DG];
  for (int i = tid; i < 8 * (DG / 4); i += DH) {
    int r = i >> 6, c = i & 63;
    ((float4*)zl[r])[c] = ((const float4*)(z + (size_t)(row0 + r) * DG))[c];
  }
  __syncthreads();
  float acc[8] = {0.f, 0.f, 0.f, 0.f, 0.f, 0.f, 0.f, 0.f};
  for (int j = 0; j < DG; j += 4) {
    float w0 = WgT[(size_t)(j + 0) * DH + tid];
    float w1 = WgT[(size_t)(j + 1) * DH + tid];
    float w2 = WgT[(size_t)(j + 2) * DH + tid];
    float w3 = WgT[(size_t)(j + 3) * DH + tid];
    #pragma unroll
    for (int r = 0; r < 8; ++r) {
      float4 zz = ((const float4*)zl[r])[j >> 2];
      acc[r] = fmaf(w0, zz.x, acc[r]);
      acc[r] = fmaf(w1, zz.y, acc[r]);
      acc[r] = fmaf(w2, zz.z, acc[r]);
      acc[r] = fmaf(w3, zz.w, acc[r]);
    }
  }
  #pragma unroll
  for (int r = 0; r < 8; ++r)
    ZG[(size_t)(row0 + r) * DH + tid] = acc[r];
}

#define HCASE(s) case (2*(s)): hreg[(s)] = hb; break; \
                 case (2*(s)+1): hreg[(s)] |= (hb << 16); break;

#define MVACC(E, wA, wB) do {                                        \
    hf2 h0 = bch((E).y), h1 = bch((E).w);                            \
    a0 += bch((wA).x) * h0; a1 += bch((wA).y) * h0;                  \
    a2 += bch((wA).z) * h0; a3 += bch((wA).w) * h0;                  \
    b0 += bch((wB).x) * h1; b1 += bch((wB).y) * h1;                  \
    b2 += bch((wB).z) * h1; b3 += bch((wB).w) * h1;                  \
  } while (0)

#define LDW(off) (*(const uint4*)(Wb + ((off) + l16)))

__global__ __launch_bounds__(512, 2)
void rnn_main(const float* __restrict__ ZG, const uint2* __restrict__ Whq,
              const float* __restrict__ bh, const float* __restrict__ gamma,
              const float* __restrict__ beta, const float* __restrict__ W_head,
              const float* __restrict__ b_head, const float* __restrict__ clean,
              float* __restrict__ outbuf) {
  const int b = blockIdx.x;
  const int tid  = threadIdx.x;         // 512 threads = 8 waves
  const int lane = tid & 63;
  const int wv   = tid >> 6;            // wave = matvec slice = active region
  const int dim  = tid;                 // owner dim (all threads own a dim)
  const int g    = tid >> 4;            // dot group 0..31 (row g; +row g+32 if g<16)
  const int dj   = tid & 15;            // chunk id within row
  const bool g16 = tid < 256;           // wave-uniform: groups 0..15 take 2 rows

  __shared__ __align__(16) unsigned histd[T_STEPS * HDSTRIDE];  // fp16 dim-pair history
  __shared__ __align__(16) float    pm[8 * DH];                 // per-slice partials
  __shared__ __align__(16) uint2    APr[8 * 64];                // per-wave-region actives
  __shared__ __align__(16) unsigned h2cur[256];                 // current h, dim-pairs
  __shared__ __align__(16) unsigned cbufh2[24];                 // c coeffs (48 fp16)
  __shared__ __align__(16) float    hcur[DH];
  __shared__ __align__(16) float    pred[DG];
  __shared__ __align__(16) float2   red[8];
  __shared__ float  red4[32];
  __shared__ int    wcntp[8];
  __shared__ float  lampow[T_STEPS];

  const float g_i  = gamma[dim];
  const float be_i = beta[dim];
  const float bh_i = bh[dim];
  if (tid == 0) {
    float pw = 0.5f;                    // eta folded in
    for (int k = 0; k < T_STEPS; ++k) { lampow[k] = pw; pw *= 0.95f; }
  }
  unsigned hreg[24];                    // owner's fp16 history column, s-pairs
  #pragma unroll
  for (int k = 0; k < 24; ++k) hreg[k] = 0u;

  const char* Wb = (const char*)Whq;    // SGPR base for saddr-form gathers
  const unsigned l16 = (unsigned)(lane << 4);
  __syncthreads();

  for (int t = 0; t < T_STEPS; ++t) {
    float zg = ZG[((size_t)t * BATCH + b) * DH + dim];

    // per-step prefetch (gated by row < t): chunks {4*dj + 64k} of dot rows
    uint4 hA0, hA1, hA2, hA3, hB0, hB1, hB2, hB3;
    hA0 = hA1 = hA2 = hA3 = make_uint4(0u, 0u, 0u, 0u);
    hB0 = hB1 = hB2 = hB3 = make_uint4(0u, 0u, 0u, 0u);
    if (g < t) {
      const unsigned* rpA = histd + g * HDSTRIDE + 4 * dj;
      hA0 = *(const uint4*)(rpA + 0);
      hA1 = *(const uint4*)(rpA + 64);
      hA2 = *(const uint4*)(rpA + 128);
      hA3 = *(const uint4*)(rpA + 192);
    }
    if (g16 && 32 + g < t) {
      const unsigned* rpB = histd + (32 + g) * HDSTRIDE + 4 * dj;
      hB0 = *(const uint4*)(rpB + 0);
      hB1 = *(const uint4*)(rpB + 64);
      hB2 = *(const uint4*)(rpB + 128);
      hB3 = *(const uint4*)(rpB + 192);
    }

    // ---- matvec: wave wv handles region wv; lane covers dims 8*lane..8*lane+7
    //      4-deep software pipeline (8 loads in flight/lane)
    {
      hf2 a0{}, a1{}, a2{}, a3{}, b0{}, b1{}, b2{}, b3{};
      if (t > 0) {
        const int n = wcntp[wv];        // multiple of 8 (or 0), uniform in wave
        if (n > 0) {
          const uint4* ap4 = (const uint4*)(APr + wv * 64);  // entry pairs
          const int G = n >> 1;          // multiple of 4, >= 4
          uint4 E0 = ap4[0], E1 = ap4[1], E2 = ap4[2], E3 = ap4[3];
          uint4 wA0 = LDW(E0.x), wB0 = LDW(E0.z);
          uint4 wA1 = LDW(E1.x), wB1 = LDW(E1.z);
          uint4 wA2 = LDW(E2.x), wB2 = LDW(E2.z);
          uint4 wA3 = LDW(E3.x), wB3 = LDW(E3.z);
          for (int grp = 4; grp < G; grp += 4) {
            uint4 F0 = ap4[grp], F1 = ap4[grp + 1];
            uint4 F2 = ap4[grp + 2], F3 = ap4[grp + 3];
            uint4 xA0 = LDW(F0.x), xB0 = LDW(F0.z);
            uint4 xA1 = LDW(F1.x), xB1 = LDW(F1.z);
            uint4 xA2 = LDW(F2.x), xB2 = LDW(F2.z);
            uint4 xA3 = LDW(F3.x), xB3 = LDW(F3.z);
            MVACC(E0, wA0, wB0); MVACC(E1, wA1, wB1);
            MVACC(E2, wA2, wB2); MVACC(E3, wA3, wB3);
            E0 = F0; E1 = F1; E2 = F2; E3 = F3;
            wA0 = xA0; wB0 = xB0; wA1 = xA1; wB1 = xB1;
            wA2 = xA2; wB2 = xB2; wA3 = xA3; wB3 = xB3;
          }
          MVACC(E0, wA0, wB0); MVACC(E1, wA1, wB1);
          MVACC(E2, wA2, wB2); MVACC(E3, wA3, wB3);
        }
      }
      float4 s0, s1;
      s0.x = (float)a0.x + (float)b0.x; s0.y = (float)a0.y + (float)b0.y;
      s0.z = (float)a1.x + (float)b1.x; s0.w = (float)a1.y + (float)b1.y;
      s1.x = (float)a2.x + (float)b2.x; s1.y = (float)a2.y + (float)b2.y;
      s1.z = (float)a3.x + (float)b3.x; s1.w = (float)a3.y + (float)b3.y;
      float4* pmw = (float4*)(pm + wv * DH);
      pmw[2 * lane + 0] = s0;
      pmw[2 * lane + 1] = s1;
    }
    __syncthreads();                                     // B0

    float base_i = bh_i + zg;
    if (t > 0) {
      float ps = 0.f;
      #pragma unroll
      for (int sl = 0; sl < 8; ++sl) ps += pm[sl * DH + dim];
      base_i += ps;
    }

    for (int inr = 0; inr <= S_INNER; ++inr) {
      // ---- phase A (all threads): x = base + Ah; DPP sums; lane63 publishes
      float x;
      {
        float Ah = 0.f;
        if (inr > 0 && t > 0) {
          const uint4* cbp = (const uint4*)cbufh2;
          float A0 = 0.f, A1 = 0.f, A2 = 0.f, A3 = 0.f;
          {
            uint4 c = cbp[0];
            A0 = fdot2u(hreg[0], c.x, A0); A1 = fdot2u(hreg[1], c.y, A1);
            A2 = fdot2u(hreg[2], c.z, A2); A3 = fdot2u(hreg[3], c.w, A3);
          }
          if (t > 8) {
            uint4 c = cbp[1];
            A0 = fdot2u(hreg[4], c.x, A0); A1 = fdot2u(hreg[5], c.y, A1);
            A2 = fdot2u(hreg[6], c.z, A2); A3 = fdot2u(hreg[7], c.w, A3);
          }
          if (t > 16) {
            uint4 c = cbp[2];
            A0 = fdot2u(hreg[8], c.x, A0);  A1 = fdot2u(hreg[9], c.y, A1);
            A2 = fdot2u(hreg[10], c.z, A2); A3 = fdot2u(hreg[11], c.w, A3);
          }
          if (t > 24) {
            uint4 c = cbp[3];
            A0 = fdot2u(hreg[12], c.x, A0); A1 = fdot2u(hreg[13], c.y, A1);
            A2 = fdot2u(hreg[14], c.z, A2); A3 = fdot2u(hreg[15], c.w, A3);
          }
          if (t > 32) {
            uint4 c = cbp[4];
            A0 = fdot2u(hreg[16], c.x, A0); A1 = fdot2u(hreg[17], c.y, A1);
            A2 = fdot2u(hreg[18], c.z, A2); A3 = fdot2u(hreg[19], c.w, A3);
          }
          if (t > 40) {
            uint4 c = cbp[5];
            A0 = fdot2u(hreg[20], c.x, A0); A1 = fdot2u(hreg[21], c.y, A1);
            A2 = fdot2u(hreg[22], c.z, A2); A3 = fdot2u(hreg[23], c.w, A3);
          }
          Ah = (A0 + A1) + (A2 + A3);
        }
        x = base_i + Ah;
        float sa = wave64_sum63(x);
        float sb = wave64_sum63(x * x);
        if (lane == 63) red[wv] = make_float2(sa, sb);
      }
      __syncthreads();                                   // B1
      float mu, rstd;
      {
        const float4* rr = (const float4*)red;
        float4 r0 = rr[0], r1 = rr[1], r2 = rr[2], r3 = rr[3];
        float s  = ((r0.x + r1.x) + (r2.x + r3.x)) + ((r0.z + r1.z) + (r2.z + r3.z));
        float s2 = ((r0.y + r1.y) + (r2.y + r3.y)) + ((r0.w + r1.w) + (r2.w + r3.w));
        const float inv = 1.f / (float)DH;
        mu = s * inv;
        float var = s2 * inv - mu * mu;
        rstd = rsqrtf(var + 1e-5f);
      }

      if (inr < S_INNER) {
        // ---- phase B (all threads): LN -> h, publish packed pairs
        {
          float h = fmaxf(fmaf((x - mu) * rstd, g_i, be_i), 0.f);
          float hn = dpp_mov<0xB1>(h);
          if (!(dim & 1)) h2cur[dim >> 1] = pkh((_Float16)h, (_Float16)hn);
        }
        __syncthreads();                                 // B2
        // ---- phase C: dots for rows g (and g+32), gated by row < t
        {
          float pA = 0.f, pB = 0.f;
          if (g < t) {
            const unsigned* hp = h2cur + 4 * dj;
            uint4 v0 = *(const uint4*)(hp + 0);
            uint4 v1 = *(const uint4*)(hp + 64);
            uint4 v2 = *(const uint4*)(hp + 128);
            uint4 v3 = *(const uint4*)(hp + 192);
            float a0 = 0.f, a1 = 0.f, a2 = 0.f, a3 = 0.f;
            a0 = fdot2u(hA0.x, v0.x, a0); a1 = fdot2u(hA0.y, v0.y, a1);
            a2 = fdot2u(hA0.z, v0.z, a2); a3 = fdot2u(hA0.w, v0.w, a3);
            a0 = fdot2u(hA1.x, v1.x, a0); a1 = fdot2u(hA1.y, v1.y, a1);
            a2 = fdot2u(hA1.z, v1.z, a2); a3 = fdot2u(hA1.w, v1.w, a3);
            a0 = fdot2u(hA2.x, v2.x, a0); a1 = fdot2u(hA2.y, v2.y, a1);
            a2 = fdot2u(hA2.z, v2.z, a2); a3 = fdot2u(hA2.w, v2.w, a3);
            a0 = fdot2u(hA3.x, v3.x, a0); a1 = fdot2u(hA3.y, v3.y, a1);
            a2 = fdot2u(hA3.z, v3.z, a2); a3 = fdot2u(hA3.w, v3.w, a3);
            pA = row16_sum((a0 + a1) + (a2 + a3));
            if (g16 && 32 + g < t) {
              float e0 = 0.f, e1 = 0.f, e2 = 0.f, e3 = 0.f;
              e0 = fdot2u(hB0.x, v0.x, e0); e1 = fdot2u(hB0.y, v0.y, e1);
              e2 = fdot2u(hB0.z, v0.z, e2); e3 = fdot2u(hB0.w, v0.w, e3);
              e0 = fdot2u(hB1.x, v1.x, e0); e1 = fdot2u(hB1.y, v1.y, e1);
              e2 = fdot2u(hB1.z, v1.z, e2); e3 = fdot2u(hB1.w, v1.w, e3);
              e0 = fdot2u(hB2.x, v2.x, e0); e1 = fdot2u(hB2.y, v2.y, e1);
              e2 = fdot2u(hB2.z, v2.z, e2); e3 = fdot2u(hB2.w, v2.w, e3);
              e0 = fdot2u(hB3.x, v3.x, e0); e1 = fdot2u(hB3.y, v3.y, e1);
              e2 = fdot2u(hB3.z, v3.z, e2); e3 = fdot2u(hB3.w, v3.w, e3);
              pB = row16_sum((e0 + e1) + (e2 + e3));
            }
          }
          if (dj == 0) {
            float ccA = (g < t) ? pA * lampow[t - 1 - g] : 0.f;
            _Float16 chA = (_Float16)ccA;
            ((unsigned short*)cbufh2)[g] = __builtin_bit_cast(unsigned short, chA);
            if (g16) {
              int rB = 32 + g;
              float ccB = (rB < t) ? pB * lampow[t - 1 - rB] : 0.f;
              _Float16 chB = (_Float16)ccB;
              ((unsigned short*)cbufh2)[rB] = __builtin_bit_cast(unsigned short, chB);
            }
          }
        }
        __syncthreads();                                 // B3
      } else {
        // ---- final inner: materialize h, append history, per-wave active list
        {
          float h = fmaxf(fmaf((x - mu) * rstd, g_i, be_i), 0.f);
          unsigned hb = (unsigned)__builtin_bit_cast(unsigned short, (_Float16)h);
          float hn = dpp_mov<0xB1>(h);
          if (!(dim & 1))
            histd[t * HDSTRIDE + (dim >> 1)] = pkh((_Float16)h, (_Float16)hn);
          switch (t) {
            HCASE(0)  HCASE(1)  HCASE(2)  HCASE(3)  HCASE(4)  HCASE(5)
            HCASE(6)  HCASE(7)  HCASE(8)  HCASE(9)  HCASE(10) HCASE(11)
            HCASE(12) HCASE(13) HCASE(14) HCASE(15) HCASE(16) HCASE(17)
            HCASE(18) HCASE(19) HCASE(20) HCASE(21) HCASE(22) HCASE(23)
          }
          if (t == T_STEPS - 1) hcur[dim] = h;
          unsigned long long mb = __ballot(h != 0.f);
          int myoff = __popcll(mb & ((1ull << lane) - 1ull));
          int wc  = __popcll(mb);
          int wcp = (wc + 7) & ~7;      // pad to multiple of 8 entries
          if (h != 0.f) {
            _Float16 hh = (_Float16)h;
            uint2 ent; ent.x = (unsigned)(dim << 10); ent.y = pkh(hh, hh);
            APr[wv * 64 + myoff] = ent;
          } else {
            int inact = lane - myoff;
            if (inact < wcp - wc) {
              uint2 zz; zz.x = 0u; zz.y = 0u;
              APr[wv * 64 + wc + inact] = zz;
            }
          }
          if (lane == 0) wcntp[wv] = wcp;
        }
        __syncthreads();                                 // B3f
      }
    }
  }

  // ---- epilogue: pred = h @ W_head^T + b_head, then loss/acc
  for (int r = wv; r < DG; r += 8) {
    const float4* w4  = (const float4*)(W_head + (size_t)r * DH);
    const float4* hc4 = (const float4*)hcur;
    float4 a4 = w4[lane];      float4 c4 = hc4[lane];
    float4 a5 = w4[lane + 64]; float4 c5 = hc4[lane + 64];
    float pdot = a4.x * c4.x + a4.y * c4.y + a4.z * c4.z + a4.w * c4.w
               + a5.x * c5.x + a5.y * c5.y + a5.z * c5.z + a5.w * c5.w;
    pdot = wave64_sum63(pdot);
    if (lane == 63) pred[r] = pdot + b_head[r];
  }
  __syncthreads();

  float sq = 0.f, pc = 0.f, pp = 0.f, cc = 0.f;
  if (tid < DG) {
    float pv = pred[tid];
    float cv = clean[(size_t)b * DG + tid];
    float d = pv - cv;
    sq = d * d; pc = pv * cv; pp = pv * pv; cc = cv * cv;
  }
  #pragma unroll
  for (int off = 32; off > 0; off >>= 1) {
    sq += __shfl_xor(sq, off, 64);
    pc += __shfl_xor(pc, off, 64);
    pp += __shfl_xor(pp, off, 64);
    cc += __shfl_xor(cc, off, 64);
  }
  if (lane == 0) {
    red4[wv * 4 + 0] = sq; red4[wv * 4 + 1] = pc;
    red4[wv * 4 + 2] = pp; red4[wv * 4 + 3] = cc;
  }
  __syncthreads();
  if (tid == 0) {
    float Sq = 0.f, Pc = 0.f, Pp = 0.f, Cc = 0.f;
    #pragma unroll
    for (int w = 0; w < 8; ++w) {
      Sq += red4[w * 4 + 0]; Pc += red4[w * 4 + 1];
      Pp += red4[w * 4 + 2]; Cc += red4[w * 4 + 3];
    }
    outbuf[b]         = Sq / (Cc + 1e-6f);
    outbuf[BATCH + b] = Pc / ((sqrtf(Pp) + 1e-6f) * (sqrtf(Cc) + 1e-6f));
  }
}

__global__ __launch_bounds__(64)
void finalize_k(const float* __restrict__ outbuf, float* __restrict__ out) {
  int tid = threadIdx.x;
  float l = (tid < BATCH) ? outbuf[tid] : 0.f;
  float a = (tid < BATCH) ? outbuf[BATCH + tid] : 0.f;
  #pragma unroll
  for (int off = 32; off > 0; off >>= 1) {
    l += __shfl_xor(l, off, 64);
    a += __shfl_xor(a, off, 64);
  }
  if (tid == 0) {
    out[0] = l * (1.f / (float)BATCH);
    out[1] = a * (1.f / (float)BATCH);
  }
}

extern "C" void kernel_launch(void* const* d_in, const int* in_sizes, int n_in,
                              void* d_out, int out_size, void* d_ws, size_t ws_size,
                              hipStream_t stream) {
  (void)in_sizes; (void)n_in; (void)out_size; (void)ws_size;
  const float* z      = (const float*)d_in[0];
  const float* clean  = (const float*)d_in[1];
  const float* W_h    = (const float*)d_in[2];
  const float* W_g    = (const float*)d_in[3];
  const float* b_h    = (const float*)d_in[4];
  const float* gamma  = (const float*)d_in[5];
  const float* beta   = (const float*)d_in[6];
  const float* W_head = (const float*)d_in[7];
  const float* b_head = (const float*)d_in[8];

  float* wsf     = (float*)d_ws;
  uint2* Whq     = (uint2*)wsf;                           // 65536 uint2
  float* WgT     = wsf + 131072;                          // 256*512
  float* ZG      = WgT + (size_t)DG * DH;                 // 2304*512
  float* outbuf  = ZG + (size_t)T_STEPS * BATCH * DH;     // 96

  hipLaunchKernelGGL(pack_whq, dim3(256), dim3(256), 0, stream, W_h, Whq);
  hipLaunchKernelGGL(transpose_k, dim3(DG / 32, DH / 32), dim3(256), 0, stream,
                     W_g, WgT, DH, DG);
  hipLaunchKernelGGL(zg_kernel, dim3((T_STEPS * BATCH) / 8), dim3(DH), 0, stream,
                     z, WgT, ZG);
  hipLaunchKernelGGL(rnn_main, dim3(BATCH), dim3(512), 0, stream,
                     ZG, Whq, b_h, gamma, beta, W_head, b_head, clean, outbuf);
  hipLaunchKernelGGL(finalize_k, dim3(1), dim3(64), 0, stream,
                     outbuf, (float*)d_out);
}